// Round 14
// baseline (669.573 us; speedup 1.0000x reference)
//
#include <hip/hip_runtime.h>
#include <math.h>

#define NA   1024
#define NGRID 4096
#define NB   2
#define NG   (NB*NGRID)   // 8192
#define NN   (NA+NG)      // 9216
#define KAK  8
#define KGK  24
#define EAE  (NA*KAK)     // 8192
#define EGE  (NG*KGK)     // 196608
#define ET   (EAE+EGE)    // 204800
#define HD   240
#define TT   16
#define DIN  489
#define CD   32
#define CUTF 8.0f

typedef __attribute__((ext_vector_type(8))) short short8;
typedef __attribute__((ext_vector_type(4))) short short4v;
typedef __attribute__((ext_vector_type(4))) float f32x4;
typedef __attribute__((ext_vector_type(4))) int i32x4;

__device__ __forceinline__ float silu_f(float x) {
    return x / (1.0f + __expf(-x));
}
__device__ __forceinline__ short f2bf(float x) {  // RNE f32->bf16
    unsigned u = __float_as_uint(x);
    unsigned r = (u + 0x7FFFu + ((u >> 16) & 1u)) >> 16;
    return (short)r;
}
__device__ __forceinline__ float bf2f(short s) {
    return __uint_as_float(((unsigned)(unsigned short)s) << 16);
}
__device__ __forceinline__ unsigned cvt_pk_bf16(float lo, float hi) {  // RNE, == f2bf pair
    unsigned r;
    asm("v_cvt_pk_bf16_f32 %0, %1, %2" : "=v"(r) : "v"(lo), "v"(hi));
    return r;
}

// ---------------- kNN (atoms + grid fused), wave-per-query, register top-K ----------------
template <int K>
__device__ __forceinline__ void wave_topk(unsigned long long key[8], int lane,
                                          int* __restrict__ outp) {
    unsigned long long lmin = key[0];
#pragma unroll
    for (int s = 1; s < 8; ++s) lmin = key[s] < lmin ? key[s] : lmin;
    int myout = -1;
    for (int t = 0; t < K; ++t) {
        unsigned long long m = lmin;
#pragma unroll
        for (int d = 1; d < 64; d <<= 1) {
            unsigned long long o = __shfl_xor(m, d);
            m = o < m ? o : m;
        }
        if (lane == t) myout = (int)(m & 1023u);
        if (m == lmin) {
#pragma unroll
            for (int s = 0; s < 8; ++s) if (key[s] == m) key[s] = ~0ull;
            lmin = key[0];
#pragma unroll
            for (int s = 1; s < 8; ++s) lmin = key[s] < lmin ? key[s] : lmin;
        }
    }
    if (lane < K) outp[lane] = myout;
}

__global__ __launch_bounds__(256) void knn_kernel(const float* __restrict__ pos,
                                                  int* __restrict__ nbr,
                                                  int* __restrict__ nbg) {
    __shared__ float sx[512], sy[512], sz[512];
    int tid = threadIdx.x;
    bool isAtom = blockIdx.x < (NA / 4);
    int q0 = isAtom ? blockIdx.x * 4 : (blockIdx.x - NA / 4) * 4;
    int pbase;
    if (isAtom) pbase = (q0 >= 512) ? 512 : 0;
    else        pbase = (q0 >= NGRID) ? 512 : 0;
    for (int j = tid; j < 512; j += 256) {
        sx[j] = pos[(pbase + j)*3 + 0];
        sy[j] = pos[(pbase + j)*3 + 1];
        sz[j] = pos[(pbase + j)*3 + 2];
    }
    __syncthreads();
    int lane = tid & 63;
    int qq = q0 + (tid >> 6);
    if (isAtom) {
        int i = qq;
        float px = sx[i - pbase], py = sy[i - pbase], pz = sz[i - pbase];
        unsigned long long key[8];
#pragma unroll
        for (int s = 0; s < 8; ++s) {
            int c = s * 64 + lane;
            int j = pbase + c;
            float dx = px - sx[c], dy = py - sy[c], dz = pz - sz[c];
            float d2 = __fadd_rn(__fadd_rn(__fmul_rn(dx,dx), __fmul_rn(dy,dy)), __fmul_rn(dz,dz));
            key[s] = ((unsigned long long)__float_as_uint(d2) << 10) | (unsigned)j;
            if (j == i) key[s] = ~0ull;
        }
        wave_topk<KAK>(key, lane, &nbr[i*KAK]);
    } else {
        int g = qq;
        int gi = g & (NGRID - 1);
        int ix = gi >> 8, iy = (gi >> 4) & 15, iz = gi & 15;
        float px = ((float)ix - 7.5f) * 1.5f;
        float py = ((float)iy - 7.5f) * 1.5f;
        float pz = ((float)iz - 7.5f) * 1.5f;
        unsigned long long key[8];
#pragma unroll
        for (int s = 0; s < 8; ++s) {
            int c = s * 64 + lane;
            int j = pbase + c;
            float dx = px - sx[c], dy = py - sy[c], dz = pz - sz[c];
            float d2 = __fadd_rn(__fadd_rn(__fmul_rn(dx,dx), __fmul_rn(dy,dy)), __fmul_rn(dz,dz));
            key[s] = ((unsigned long long)__float_as_uint(d2) << 10) | (unsigned)j;
        }
        wave_topk<KGK>(key, lane, &nbg[g*KGK]);
    }
}

// ---------------- edge features (sph * mask), split aligned storage ----------------
__global__ void edge_kernel(const float* __restrict__ pos, const int* __restrict__ nbr,
                            const int* __restrict__ nbg, float4* __restrict__ eaA,
                            float4* __restrict__ eaB, float* __restrict__ eaC,
                            float* __restrict__ emask) {
    int e = blockIdx.x * blockDim.x + threadIdx.x;
    if (e >= ET) return;
    int src; float dpx, dpy, dpz;
    if (e < EAE) {
        int d = e >> 3;
        src = nbr[e];
        dpx = pos[d*3]; dpy = pos[d*3+1]; dpz = pos[d*3+2];
    } else {
        int eg = e - EAE;
        src = nbg[eg];
        int gg = eg / KGK;
        int gi = gg % NGRID;
        int ix = gi >> 8, iy = (gi >> 4) & 15, iz = gi & 15;
        dpx = ((float)ix - 7.5f) * 1.5f;
        dpy = ((float)iy - 7.5f) * 1.5f;
        dpz = ((float)iz - 7.5f) * 1.5f;
    }
    float rx = pos[src*3] - dpx, ry = pos[src*3+1] - dpy, rz = pos[src*3+2] - dpz;
    float dist = sqrtf(rx*rx + ry*ry + rz*rz);
    float mask = (dist <= CUTF) ? 1.0f : 0.0f;
    float inv = 1.0f / fmaxf(dist, 1e-9f);
    float x = rx * inv, y = ry * inv, z = rz * inv;
    float s0 = 0.28209479177387814f;
    float s1 = 0.4886025119029199f * y;
    float s2 = 0.4886025119029199f * z;
    float s3 = 0.4886025119029199f * x;
    float s4 = 1.0925484305920792f * x * y;
    float s5 = 1.0925484305920792f * y * z;
    float s6 = 0.31539156525252005f * (3.0f * z * z - 1.0f);
    float s7 = 1.0925484305920792f * z * x;
    float s8 = 0.5462742152960396f * (x * x - y * y);
    eaA[e] = (float4){s0*mask, s1*mask, s2*mask, s3*mask};
    eaB[e] = (float4){s4*mask, s5*mask, s6*mask, s7*mask};
    eaC[e] = s8 * mask;
    emask[e] = mask;
}

// ---------------- node_attr (segment mean of ea) ----------------
__global__ void node_attr_kernel(const float4* __restrict__ eaA, const float4* __restrict__ eaB,
                                 const float* __restrict__ eaC, const float* __restrict__ emask,
                                 float* __restrict__ attr) {
    int n = blockIdx.x * blockDim.x + threadIdx.x;
    if (n >= NN) return;
    int K, e0;
    if (n < NA) { K = KAK; e0 = n * KAK; }
    else        { K = KGK; e0 = EAE + (n - NA) * KGK; }
    float s[9];
#pragma unroll
    for (int a = 0; a < 9; ++a) s[a] = 0.f;
    float cnt = 0.f;
    for (int k = 0; k < K; ++k) {
        cnt += emask[e0 + k];
        const float4 a0 = eaA[e0 + k];
        const float4 a1 = eaB[e0 + k];
        s[0] += a0.x; s[1] += a0.y; s[2] += a0.z; s[3] += a0.w;
        s[4] += a1.x; s[5] += a1.y; s[6] += a1.z; s[7] += a1.w;
        s[8] += eaC[e0 + k];
    }
    float invc = 1.0f / fmaxf(cnt, 1.0f);
    attr[n*9+0] = 1.0f;
#pragma unroll
    for (int a = 1; a < 9; ++a) attr[n*9+a] = s[a] * invc;
}

// ---------------- fused weight converter (all 5 jobs in one dispatch) ----------------
__global__ void convert_all_kernel(const float* __restrict__ Wm2, const float* __restrict__ Wu1,
                                   const float* __restrict__ Wu2, const float* __restrict__ Wm1,
                                   short* __restrict__ wm2t, short* __restrict__ wu1t,
                                   short* __restrict__ wu2t,
                                   short* __restrict__ wzd_hi, short* __restrict__ wzd_lo,
                                   short* __restrict__ wzs_hi, short* __restrict__ wzs_lo) {
    int idx = blockIdx.x * blockDim.x + threadIdx.x;
    if (idx < 131072) {                       // wm2t: [l][col 256][k 256], K=240
        int l = idx >> 16, rem = idx & 65535, col = rem >> 8, k = rem & 255;
        short v = 0;
        if (k < 240 && col < 240) v = f2bf(Wm2[(size_t)l*57600 + k*240 + col]);
        wm2t[idx] = v;
    } else if (idx < 393216) {                // wu1t: [l][col 256][k 512], K=489
        int i = idx - 131072;
        int l = i / 131072, rem = i % 131072, col = rem >> 9, k = rem & 511;
        short v = 0;
        if (k < DIN && col < 240) v = f2bf(Wu1[(size_t)l*DIN*240 + (size_t)k*240 + col]);
        wu1t[i] = v;
    } else if (idx < 524288) {                // wu2t: K=240
        int i = idx - 393216;
        int l = i >> 16, rem = i & 65535, col = rem >> 8, k = rem & 255;
        short v = 0;
        if (k < 240 && col < 240) v = f2bf(Wu2[(size_t)l*57600 + k*240 + col]);
        wu2t[i] = v;
    } else if (idx < 655360) {                // wzd hi/lo (Wm1 rows 240..479)
        int i = idx - 524288;
        int l = i >> 16, rem = i & 65535, col = rem >> 8, k = rem & 255;
        float v = 0.f;
        if (k < 240 && col < 240) v = Wm1[(size_t)l*DIN*HD + (size_t)(240 + k)*HD + col];
        short hh = f2bf(v);
        wzd_hi[i] = hh;
        wzd_lo[i] = f2bf(v - bf2f(hh));
    } else {                                  // wzs hi/lo (Wm1 rows 0..239)
        int i = idx - 655360;
        int l = i >> 16, rem = i & 65535, col = rem >> 8, k = rem & 255;
        float v = 0.f;
        if (k < 240 && col < 240) v = Wm1[(size_t)l*DIN*HD + (size_t)k*HD + col];
        short hh = f2bf(v);
        wzs_hi[i] = hh;
        wzs_lo[i] = f2bf(v - bf2f(hh));
    }
}

// ---------------- shared Z-MFMA body: Zd (+Zs if atom block) from Ahi/Alo LDS ----------------
__device__ __forceinline__ void z_mfma_body(
        const short* __restrict__ Ahi, const short* __restrict__ Alo,
        const short* __restrict__ wzd_hi, const short* __restrict__ wzd_lo,
        const short* __restrict__ wzs_hi, const short* __restrict__ wzs_lo,
        const float* __restrict__ bm1, float* __restrict__ Zs, float* __restrict__ Zd,
        int n0, int tid) {
    int wid = tid >> 6, lane = tid & 63;
    int mw = wid >> 1, nw = wid & 1;
    int lg = lane >> 4, lc = lane & 15;
    int col0 = nw * 128;
    int arow = (mw * 16 + lc) * 256;

    f32x4 acc[8];
#pragma unroll
    for (int nt = 0; nt < 8; ++nt) acc[nt] = (f32x4){0.f, 0.f, 0.f, 0.f};
    __builtin_amdgcn_s_setprio(1);
#pragma unroll
    for (int kc = 0; kc < 8; ++kc) {
        int aoff = arow + ((kc * 32 + lg * 8) ^ ((lc & 7) << 3));
        const short8 ahi = *(const short8*)&Ahi[aoff];
        const short8 alo = *(const short8*)&Alo[aoff];
#pragma unroll
        for (int nt = 0; nt < 8; ++nt) {
            size_t bo = (size_t)(col0 + nt*16 + lc) * 256 + kc*32 + lg*8;
            const short8 bhi = *(const short8*)(wzd_hi + bo);
            const short8 blo = *(const short8*)(wzd_lo + bo);
            acc[nt] = __builtin_amdgcn_mfma_f32_16x16x32_bf16(ahi, bhi, acc[nt], 0, 0, 0);
            acc[nt] = __builtin_amdgcn_mfma_f32_16x16x32_bf16(ahi, blo, acc[nt], 0, 0, 0);
            acc[nt] = __builtin_amdgcn_mfma_f32_16x16x32_bf16(alo, bhi, acc[nt], 0, 0, 0);
        }
    }
    __builtin_amdgcn_s_setprio(0);
#pragma unroll
    for (int nt = 0; nt < 8; ++nt) {
        int ncol = col0 + nt * 16 + lc;
        if (ncol < HD) {
            float bias = bm1[ncol];
            float vals[4] = {acc[nt].x, acc[nt].y, acc[nt].z, acc[nt].w};
#pragma unroll
            for (int r = 0; r < 4; ++r)
                Zd[(size_t)(n0 + mw*16 + lg*4 + r) * HD + ncol] = vals[r] + bias;
        }
    }

    if (n0 < NA) {
#pragma unroll
        for (int nt = 0; nt < 8; ++nt) acc[nt] = (f32x4){0.f, 0.f, 0.f, 0.f};
        __builtin_amdgcn_s_setprio(1);
#pragma unroll
        for (int kc = 0; kc < 8; ++kc) {
            int aoff = arow + ((kc * 32 + lg * 8) ^ ((lc & 7) << 3));
            const short8 ahi = *(const short8*)&Ahi[aoff];
            const short8 alo = *(const short8*)&Alo[aoff];
#pragma unroll
            for (int nt = 0; nt < 8; ++nt) {
                size_t bo = (size_t)(col0 + nt*16 + lc) * 256 + kc*32 + lg*8;
                const short8 bhi = *(const short8*)(wzs_hi + bo);
                const short8 blo = *(const short8*)(wzs_lo + bo);
                acc[nt] = __builtin_amdgcn_mfma_f32_16x16x32_bf16(ahi, bhi, acc[nt], 0, 0, 0);
                acc[nt] = __builtin_amdgcn_mfma_f32_16x16x32_bf16(ahi, blo, acc[nt], 0, 0, 0);
                acc[nt] = __builtin_amdgcn_mfma_f32_16x16x32_bf16(alo, bhi, acc[nt], 0, 0, 0);
            }
        }
        __builtin_amdgcn_s_setprio(0);
#pragma unroll
        for (int nt = 0; nt < 8; ++nt) {
            int ncol = col0 + nt * 16 + lc;
            if (ncol < HD) {
                float vals[4] = {acc[nt].x, acc[nt].y, acc[nt].z, acc[nt].w};
#pragma unroll
                for (int r = 0; r < 4; ++r)
                    Zs[(size_t)(n0 + mw*16 + lg*4 + r) * HD + ncol] = vals[r];
            }
        }
    }
}

// ---------------- fused encoder + layer-0 node Z: h = silu([feat|attr]@We+be); Z = f(h) ----------------
__global__ __launch_bounds__(256) void encoder_z_kernel(
        const int* __restrict__ types, const float* __restrict__ attr,
        const float* __restrict__ We, const float* __restrict__ be,
        const short* __restrict__ wzd_hi, const short* __restrict__ wzd_lo,
        const short* __restrict__ wzs_hi, const short* __restrict__ wzs_lo,
        const float* __restrict__ bm1,
        float* __restrict__ h, float* __restrict__ Zs, float* __restrict__ Zd) {
    __shared__ __align__(16) short Ahi[32 * 256];
    __shared__ __align__(16) short Alo[32 * 256];
    __shared__ float sattr[32 * 9];
    int tid = threadIdx.x;
    int n0 = blockIdx.x * 32;
    for (int i = tid; i < 288; i += 256) sattr[i] = attr[n0 * 9 + i];
    __syncthreads();

#pragma unroll
    for (int it = 0; it < 4; ++it) {
        int idx = it * 256 + tid;
        int row = idx >> 5, q = idx & 31;
        int j = q * 8;
        int n = n0 + row;
        short8 ohi = {0,0,0,0,0,0,0,0}, olo = {0,0,0,0,0,0,0,0};
        if (j < 240) {
            int tpe = (n < NA) ? types[n] : -1;
            float4 hv0, hv1;
            float* hvp[8] = {&hv0.x, &hv0.y, &hv0.z, &hv0.w, &hv1.x, &hv1.y, &hv1.z, &hv1.w};
#pragma unroll
            for (int c = 0; c < 8; ++c) {
                int col = j + c;
                float acc = be[col];
                if (tpe >= 0) acc += We[tpe * HD + col];
#pragma unroll
                for (int a = 0; a < 9; ++a) acc += sattr[row * 9 + a] * We[(TT + a) * HD + col];
                float v = silu_f(acc);
                *hvp[c] = v;
                short hh = f2bf(v);
                ohi[c] = hh;
                olo[c] = f2bf(v - bf2f(hh));
            }
            *(float4*)(h + (size_t)n * HD + j) = hv0;
            *(float4*)(h + (size_t)n * HD + j + 4) = hv1;
        }
        int boff = row * 512 + ((q * 16) ^ ((row & 7) << 4));
        *(short8*)((char*)Ahi + boff) = ohi;
        *(short8*)((char*)Alo + boff) = olo;
    }
    __syncthreads();
    z_mfma_body(Ahi, Alo, wzd_hi, wzd_lo, wzs_hi, wzs_lo, bm1, Zs, Zd, n0, tid);
}

// ---------------- fused grid-edge message MLP (r13 structure, known 134us) ----------------
__global__ __launch_bounds__(256) void msg_gemm_kernel(
        const float* __restrict__ Zs, const float* __restrict__ Zd,
        const int* __restrict__ nbg,
        const float4* __restrict__ eaA, const float4* __restrict__ eaB,
        const float* __restrict__ eaC,
        const float* __restrict__ emask, const float* __restrict__ Wea,
        const short* __restrict__ wm2t, const float* __restrict__ bm2,
        float* __restrict__ agg) {
    __shared__ __align__(16) short Abuf[48 * 256];   // 24KB, XOR-swizzled
    __shared__ __align__(16) float mkbuf[48];
    int tid = threadIdx.x;
    int blk = blockIdx.x;
    int e0 = blk * 48;

    int q = tid & 31;
    int rh = tid >> 5;
    float4 w0[9], w1[9];
    float4 zdA0, zdA1, zdB0, zdB1;
    int srcs[6];
    if (q < 30) {
        int j = q * 8;
#pragma unroll
        for (int a = 0; a < 9; ++a) {
            w0[a] = *(const float4*)(Wea + a * HD + j);
            w1[a] = *(const float4*)(Wea + a * HD + j + 4);
        }
#pragma unroll
        for (int r8 = 0; r8 < 6; ++r8) srcs[r8] = nbg[e0 + rh + r8 * 8];
        int dn0 = NA + blk * 2;
        zdA0 = *(const float4*)(Zd + (size_t)dn0 * HD + j);
        zdA1 = *(const float4*)(Zd + (size_t)dn0 * HD + j + 4);
        zdB0 = *(const float4*)(Zd + (size_t)(dn0 + 1) * HD + j);
        zdB1 = *(const float4*)(Zd + (size_t)(dn0 + 1) * HD + j + 4);
    }
    if (tid < 48) mkbuf[tid] = emask[EAE + e0 + tid];

#pragma unroll
    for (int r8 = 0; r8 < 6; ++r8) {
        int row = rh + r8 * 8;
        i32x4 oi = (i32x4){0, 0, 0, 0};
        if (q < 30) {
            int j = q * 8;
            int eg = e0 + row;
            int srcn = srcs[r8];
            const float4 zs0 = *(const float4*)(Zs + (size_t)srcn * HD + j);
            const float4 zs1 = *(const float4*)(Zs + (size_t)srcn * HD + j + 4);
            const float4 zd0 = (r8 < 3) ? zdA0 : zdB0;
            const float4 zd1 = (r8 < 3) ? zdA1 : zdB1;
            float s0 = zs0.x + zd0.x, s1 = zs0.y + zd0.y, s2 = zs0.z + zd0.z, s3 = zs0.w + zd0.w;
            float s4 = zs1.x + zd1.x, s5 = zs1.y + zd1.y, s6 = zs1.z + zd1.z, s7 = zs1.w + zd1.w;
            const float4 ea0 = eaA[EAE + eg];
            const float4 ea1 = eaB[EAE + eg];
            const float  ea8 = eaC[EAE + eg];
            float ev[9] = {ea0.x, ea0.y, ea0.z, ea0.w, ea1.x, ea1.y, ea1.z, ea1.w, ea8};
#pragma unroll
            for (int a = 0; a < 9; ++a) {
                float e = ev[a];
                s0 += e * w0[a].x; s1 += e * w0[a].y; s2 += e * w0[a].z; s3 += e * w0[a].w;
                s4 += e * w1[a].x; s5 += e * w1[a].y; s6 += e * w1[a].z; s7 += e * w1[a].w;
            }
            oi[0] = (int)cvt_pk_bf16(silu_f(s0), silu_f(s1));
            oi[1] = (int)cvt_pk_bf16(silu_f(s2), silu_f(s3));
            oi[2] = (int)cvt_pk_bf16(silu_f(s4), silu_f(s5));
            oi[3] = (int)cvt_pk_bf16(silu_f(s6), silu_f(s7));
        }
        *(i32x4*)((char*)Abuf + row * 512 + ((q * 16) ^ ((row & 7) << 4))) = oi;
    }
    __syncthreads();

    int wid = tid >> 6, lane = tid & 63;
    int lg = lane >> 4, lc = lane & 15;
    int col0 = wid * 64;

    f32x4 acc[3][4];
#pragma unroll
    for (int mt = 0; mt < 3; ++mt)
#pragma unroll
        for (int nt = 0; nt < 4; ++nt) acc[mt][nt] = (f32x4){0.f, 0.f, 0.f, 0.f};

    __builtin_amdgcn_s_setprio(1);
#pragma unroll
    for (int kc = 0; kc < 8; ++kc) {
        short8 af[3];
#pragma unroll
        for (int mt = 0; mt < 3; ++mt)
            af[mt] = *(const short8*)&Abuf[(mt*16 + lc) * 256 +
                                           ((kc*32 + lg*8) ^ ((lc & 7) << 3))];
#pragma unroll
        for (int nt = 0; nt < 4; ++nt) {
            const short8 bf = *(const short8*)(wm2t + (size_t)(col0 + nt*16 + lc) * 256 + kc*32 + lg*8);
#pragma unroll
            for (int mt = 0; mt < 3; ++mt)
                acc[mt][nt] = __builtin_amdgcn_mfma_f32_16x16x32_bf16(af[mt], bf, acc[mt][nt], 0, 0, 0);
        }
    }
    __builtin_amdgcn_s_setprio(0);

#pragma unroll
    for (int nt = 0; nt < 4; ++nt) {
        int ncol = col0 + nt * 16 + lc;
        float bias = (ncol < HD) ? bm2[ncol] : 0.f;
        float p[3];
#pragma unroll
        for (int mt = 0; mt < 3; ++mt) {
            const float4 mkv = *(const float4*)&mkbuf[mt*16 + lg*4];
            float t0 = silu_f(acc[mt][nt].x + bias) * mkv.x;
            float t1 = silu_f(acc[mt][nt].y + bias) * mkv.y;
            float t2 = silu_f(acc[mt][nt].z + bias) * mkv.z;
            float t3 = silu_f(acc[mt][nt].w + bias) * mkv.w;
            p[mt] = (t0 + t1) + (t2 + t3);
        }
        float v0 = p[0] + ((lg < 2) ? p[1] : 0.f);
        float v1 = ((lg >= 2) ? p[1] : 0.f) + p[2];
        v0 += __shfl_xor(v0, 16); v0 += __shfl_xor(v0, 32);
        v1 += __shfl_xor(v1, 16); v1 += __shfl_xor(v1, 32);
        if (ncol < HD) {
            int node = NA + blk * 2;
            if (lane < 16)      agg[(size_t)(node + 0) * HD + ncol] = v0;
            else if (lane < 32) agg[(size_t)(node + 1) * HD + ncol] = v1;
        }
    }
}

// ---------------- fused message MLP for ATOM edges ----------------
template <int KE, int NPB>
__global__ __launch_bounds__(192) void msg_mfma_kernel(
        const float* __restrict__ Zs, const float* __restrict__ Zd,
        const int* __restrict__ nbrList,
        const float4* __restrict__ eaA, const float4* __restrict__ eaB,
        const float* __restrict__ eaC,
        const float* __restrict__ emask, const float* __restrict__ Wea,
        const short* __restrict__ wm2t, const float* __restrict__ bm2,
        float* __restrict__ agg, int dstBase, int edgeBase) {
    constexpr int ROWS = KE * NPB;
    constexpr int MT = ROWS / 16;
    __shared__ __align__(16) short Abuf[ROWS * 264];
    __shared__ __align__(16) float mkbuf[ROWS];

    int tid = threadIdx.x;
    int b = blockIdx.x;
    int e0 = edgeBase + b * ROWS;

    if (tid < ROWS) mkbuf[tid] = emask[e0 + tid];
    for (int idx = tid; idx < ROWS * 24; idx += 192) {
        int r = idx / 24;
        Abuf[r * 264 + 240 + (idx % 24)] = 0;
    }
    for (int idx = tid; idx < ROWS * 60; idx += 192) {
        int row = idx / 60;
        int j = (idx % 60) * 4;
        int srcn = nbrList[b * ROWS + row];
        int dstn = dstBase + b * NPB + row / KE;
        const float4 zs = *(const float4*)(Zs + (size_t)srcn * HD + j);
        const float4 zd = *(const float4*)(Zd + (size_t)dstn * HD + j);
        float s0 = zs.x + zd.x, s1 = zs.y + zd.y, s2 = zs.z + zd.z, s3 = zs.w + zd.w;
        const float4 ea0 = eaA[e0 + row];
        const float4 ea1 = eaB[e0 + row];
        const float  ea8 = eaC[e0 + row];
        float ev[9] = {ea0.x, ea0.y, ea0.z, ea0.w, ea1.x, ea1.y, ea1.z, ea1.w, ea8};
#pragma unroll
        for (int a = 0; a < 9; ++a) {
            float e = ev[a];
            const float4 w = *(const float4*)(Wea + a * HD + j);
            s0 += e * w.x; s1 += e * w.y; s2 += e * w.z; s3 += e * w.w;
        }
        short4v o;
        o.x = f2bf(silu_f(s0)); o.y = f2bf(silu_f(s1));
        o.z = f2bf(silu_f(s2)); o.w = f2bf(silu_f(s3));
        *(short4v*)&Abuf[row * 264 + j] = o;
    }
    __syncthreads();

    int w = tid / 64, lane = tid % 64;
    int lg = lane >> 4, lc = lane & 15;
    int wcol0 = w * 80;

    f32x4 acc[MT][5];
#pragma unroll
    for (int mt = 0; mt < MT; ++mt)
#pragma unroll
        for (int nt = 0; nt < 5; ++nt) acc[mt][nt] = (f32x4){0.f, 0.f, 0.f, 0.f};

#pragma unroll
    for (int kc = 0; kc < 8; ++kc) {
        short8 af[MT];
#pragma unroll
        for (int mt = 0; mt < MT; ++mt)
            af[mt] = *(const short8*)&Abuf[(mt * 16 + lc) * 264 + kc * 32 + lg * 8];
#pragma unroll
        for (int nt = 0; nt < 5; ++nt) {
            const short8 bf = *(const short8*)(wm2t + (size_t)(wcol0 + nt * 16 + lc) * 256 + kc * 32 + lg * 8);
#pragma unroll
            for (int mt = 0; mt < MT; ++mt)
                acc[mt][nt] = __builtin_amdgcn_mfma_f32_16x16x32_bf16(af[mt], bf, acc[mt][nt], 0, 0, 0);
        }
    }

#pragma unroll
    for (int nt = 0; nt < 5; ++nt) {
        int ncol = wcol0 + nt * 16 + lc;
        float bias = bm2[ncol];
        float p[MT];
#pragma unroll
        for (int mt = 0; mt < MT; ++mt) {
            const float4 mkv = *(const float4*)&mkbuf[mt * 16 + lg * 4];
            float t0 = silu_f(acc[mt][nt].x + bias) * mkv.x;
            float t1 = silu_f(acc[mt][nt].y + bias) * mkv.y;
            float t2 = silu_f(acc[mt][nt].z + bias) * mkv.z;
            float t3 = silu_f(acc[mt][nt].w + bias) * mkv.w;
            p[mt] = (t0 + t1) + (t2 + t3);
        }
#pragma unroll
        for (int mt = 0; mt < MT; ++mt) {
            float v = p[mt];
            v += __shfl_xor(v, 16);
            if (lane < 16)
                agg[(size_t)(dstBase + b * (2 * MT) + 2 * mt + 0) * HD + ncol] = v;
            else if (lane >= 32 && lane < 48)
                agg[(size_t)(dstBase + b * (2 * MT) + 2 * mt + 1) * HD + ncol] = v;
        }
    }
}

// ---------------- fused node update + (optional) next-layer node Z ----------------
template <bool DO_Z>
__global__ __launch_bounds__(256) void update_z_kernel(
        float* __restrict__ h, const float* __restrict__ agg,
        const float* __restrict__ attr,
        const short* __restrict__ wu1t, const float* __restrict__ bu1,
        const short* __restrict__ wu2t, const float* __restrict__ bu2,
        const short* __restrict__ wzd_hi, const short* __restrict__ wzd_lo,
        const short* __restrict__ wzs_hi, const short* __restrict__ wzs_lo,
        const float* __restrict__ bm1,
        float* __restrict__ Zs, float* __restrict__ Zd) {
    __shared__ __align__(16) short Abuf[32 * 512];   // phase A: ui; phase B: Ahi+Alo
    __shared__ __align__(16) short Ubuf[32 * 256];
    short* Ahi = Abuf;
    short* Alo = Abuf + 32 * 256;
    int tid = threadIdx.x;
    int n0 = blockIdx.x * 32;

#pragma unroll
    for (int it = 0; it < 8; ++it) {
        int idx = it * 256 + tid;
        int row = idx >> 6, q = idx & 63;
        int j = q * 8;
        int n = n0 + row;
        short8 o = {0,0,0,0,0,0,0,0};
        if (j < 240) {
            const float4 a0 = *(const float4*)(h + (size_t)n * HD + j);
            const float4 a1 = *(const float4*)(h + (size_t)n * HD + j + 4);
            o[0]=f2bf(a0.x); o[1]=f2bf(a0.y); o[2]=f2bf(a0.z); o[3]=f2bf(a0.w);
            o[4]=f2bf(a1.x); o[5]=f2bf(a1.y); o[6]=f2bf(a1.z); o[7]=f2bf(a1.w);
        } else if (j < 480) {
            const float4 a0 = *(const float4*)(agg + (size_t)n * HD + (j - 240));
            const float4 a1 = *(const float4*)(agg + (size_t)n * HD + (j - 240) + 4);
            o[0]=f2bf(a0.x); o[1]=f2bf(a0.y); o[2]=f2bf(a0.z); o[3]=f2bf(a0.w);
            o[4]=f2bf(a1.x); o[5]=f2bf(a1.y); o[6]=f2bf(a1.z); o[7]=f2bf(a1.w);
        } else if (j == 480) {
#pragma unroll
            for (int a = 0; a < 8; ++a) o[a] = f2bf(attr[n*9 + a]);
        } else if (j == 488) {
            o[0] = f2bf(attr[n*9 + 8]);
        }
        *(short8*)((char*)Abuf + row * 1024 + ((q * 16) ^ ((row & 7) << 4))) = o;
    }
    __syncthreads();

    int wid = tid >> 6, lane = tid & 63;
    int mw = wid >> 1, nw = wid & 1;
    int lg = lane >> 4, lc = lane & 15;
    int col0 = nw * 128;

    f32x4 acc[8];
#pragma unroll
    for (int nt = 0; nt < 8; ++nt) acc[nt] = (f32x4){0.f, 0.f, 0.f, 0.f};
    __builtin_amdgcn_s_setprio(1);
#pragma unroll
    for (int kc = 0; kc < 16; ++kc) {
        const short8 af = *(const short8*)((char*)Abuf + (mw*16 + lc) * 1024 +
                                           ((kc*64 + lg*16) ^ ((lc & 7) << 4)));
#pragma unroll
        for (int nt = 0; nt < 8; ++nt) {
            const short8 bf = *(const short8*)(wu1t + (size_t)(col0 + nt*16 + lc) * 512 + kc*32 + lg*8);
            acc[nt] = __builtin_amdgcn_mfma_f32_16x16x32_bf16(af, bf, acc[nt], 0, 0, 0);
        }
    }
    __builtin_amdgcn_s_setprio(0);
#pragma unroll
    for (int nt = 0; nt < 8; ++nt) {
        int ncol = col0 + nt * 16 + lc;
        float bias = (ncol < HD) ? bu1[ncol] : 0.f;
        float vals[4] = {acc[nt].x, acc[nt].y, acc[nt].z, acc[nt].w};
#pragma unroll
        for (int r = 0; r < 4; ++r) {
            int row = mw*16 + lg*4 + r;
            *(short*)((char*)Ubuf + row * 512 + ((ncol * 2) ^ ((row & 7) << 4))) =
                f2bf(silu_f(vals[r] + bias));
        }
    }
    __syncthreads();   // after this barrier, all Abuf reads are done -> reusable as Ahi/Alo

    f32x4 acc2[8];
#pragma unroll
    for (int nt = 0; nt < 8; ++nt) acc2[nt] = (f32x4){0.f, 0.f, 0.f, 0.f};
    __builtin_amdgcn_s_setprio(1);
#pragma unroll
    for (int kc = 0; kc < 8; ++kc) {
        const short8 af = *(const short8*)((char*)Ubuf + (mw*16 + lc) * 512 +
                                           ((kc*64 + lg*16) ^ ((lc & 7) << 4)));
#pragma unroll
        for (int nt = 0; nt < 8; ++nt) {
            const short8 bf = *(const short8*)(wu2t + (size_t)(col0 + nt*16 + lc) * 256 + kc*32 + lg*8);
            acc2[nt] = __builtin_amdgcn_mfma_f32_16x16x32_bf16(af, bf, acc2[nt], 0, 0, 0);
        }
    }
    __builtin_amdgcn_s_setprio(0);
#pragma unroll
    for (int nt = 0; nt < 8; ++nt) {
        int ncol = col0 + nt * 16 + lc;
        float bias = (ncol < HD) ? bu2[ncol] : 0.f;
        float vals[4] = {acc2[nt].x, acc2[nt].y, acc2[nt].z, acc2[nt].w};
#pragma unroll
        for (int r = 0; r < 4; ++r) {
            int row = mw*16 + lg*4 + r;
            int zoff = row * 512 + ((ncol * 2) ^ ((row & 7) << 4));
            if (ncol < HD) {
                size_t hidx = (size_t)(n0 + row) * HD + ncol;
                float nh = h[hidx] + silu_f(vals[r] + bias);
                h[hidx] = nh;
                if (DO_Z) {
                    short hh = f2bf(nh);
                    *(short*)((char*)Ahi + zoff) = hh;
                    *(short*)((char*)Alo + zoff) = f2bf(nh - bf2f(hh));
                }
            } else if (DO_Z) {
                *(short*)((char*)Ahi + zoff) = 0;
                *(short*)((char*)Alo + zoff) = 0;
            }
        }
    }
    if (!DO_Z) return;
    __syncthreads();
    z_mfma_body(Ahi, Alo, wzd_hi, wzd_lo, wzs_hi, wzs_lo, bm1, Zs, Zd, n0, tid);
}

// ---------------- readout (grid nodes only) ----------------
__global__ void output_kernel(const float* __restrict__ h,
                              const float* __restrict__ Wo1, const float* __restrict__ bo1,
                              const float* __restrict__ Wo2, const float* __restrict__ bo2,
                              float* __restrict__ out) {
    const int NBT = 4;
    __shared__ float hr[NBT][HD];
    __shared__ float o1[NBT][HD];
    int tid = threadIdx.x;
    int g0 = blockIdx.x * NBT;
    for (int idx = tid; idx < NBT * HD; idx += 256) {
        int k = idx / HD, i = idx % HD;
        hr[k][i] = h[(size_t)(NA + g0 + k) * HD + i];
    }
    __syncthreads();
    int j = tid;
    if (j < HD) {
        float acc[NBT] = {0.f, 0.f, 0.f, 0.f};
        for (int i4 = 0; i4 < 60; ++i4) {
            int i = 4 * i4;
            float w0 = Wo1[(i+0)*HD+j], w1 = Wo1[(i+1)*HD+j];
            float w2 = Wo1[(i+2)*HD+j], w3 = Wo1[(i+3)*HD+j];
#pragma unroll
            for (int k = 0; k < NBT; ++k) {
                const float4 a = *reinterpret_cast<const float4*>(&hr[k][i]);
                acc[k] += a.x*w0 + a.y*w1 + a.z*w2 + a.w*w3;
            }
        }
        float bb = bo1[j];
#pragma unroll
        for (int k = 0; k < NBT; ++k) o1[k][j] = silu_f(acc[k] + bb);
    }
    __syncthreads();
    if (tid < NBT * CD) {
        int k = tid >> 5, c = tid & 31;
        float acc = bo2[c];
        for (int i = 0; i < HD; ++i) acc += o1[k][i] * Wo2[i*CD + c];
        out[(size_t)(g0 + k) * CD + c] = acc;
    }
}

extern "C" void kernel_launch(void* const* d_in, const int* in_sizes, int n_in,
                              void* d_out, int out_size, void* d_ws, size_t ws_size,
                              hipStream_t stream) {
    (void)in_sizes; (void)n_in; (void)out_size; (void)ws_size;
    const float* pos   = (const float*)d_in[0];
    const int*   types = (const int*)d_in[1];
    const int*   batch = (const int*)d_in[2];
    (void)batch;
    const float* We    = (const float*)d_in[3];
    const float* be    = (const float*)d_in[4];
    const float* Wm1   = (const float*)d_in[5];
    const float* bm1   = (const float*)d_in[6];
    const float* Wm2   = (const float*)d_in[7];
    const float* bm2   = (const float*)d_in[8];
    const float* Wu1   = (const float*)d_in[9];
    const float* bu1   = (const float*)d_in[10];
    const float* Wu2   = (const float*)d_in[11];
    const float* bu2   = (const float*)d_in[12];
    const float* Wo1   = (const float*)d_in[13];
    const float* bo1   = (const float*)d_in[14];
    const float* Wo2   = (const float*)d_in[15];
    const float* bo2   = (const float*)d_in[16];
    float* out = (float*)d_out;

    char* ws = (char*)d_ws;
    size_t off = 0;
    auto take = [&](size_t bytes) -> char* {
        char* p = ws + off;
        off = (off + bytes + 255) & ~(size_t)255;
        return p;
    };
    int*    nbr    = (int*)take((size_t)EAE * 4);
    int*    nbg    = (int*)take((size_t)EGE * 4);
    float4* eaA    = (float4*)take((size_t)ET * 16);
    float4* eaB    = (float4*)take((size_t)ET * 16);
    float*  eaC    = (float*)take((size_t)ET * 4);
    float*  emask  = (float*)take((size_t)ET * 4);
    float*  attr   = (float*)take((size_t)NN * 9 * 4);
    float*  h      = (float*)take((size_t)NN * HD * 4);
    float*  agg    = (float*)take((size_t)NN * HD * 4);
    float*  zs     = (float*)take((size_t)NA * HD * 4);
    float*  zd     = (float*)take((size_t)NN * HD * 4);
    short*  wm2t   = (short*)take((size_t)2 * 256 * 256 * 2);
    short*  wu1t   = (short*)take((size_t)2 * 256 * 512 * 2);
    short*  wu2t   = (short*)take((size_t)2 * 256 * 256 * 2);
    short*  wzd_hi = (short*)take((size_t)2 * 256 * 256 * 2);
    short*  wzd_lo = (short*)take((size_t)2 * 256 * 256 * 2);
    short*  wzs_hi = (short*)take((size_t)2 * 256 * 256 * 2);
    short*  wzs_lo = (short*)take((size_t)2 * 256 * 256 * 2);

    knn_kernel<<<NA/4 + NG/4, 256, 0, stream>>>(pos, nbr, nbg);
    edge_kernel<<<ET/256, 256, 0, stream>>>(pos, nbr, nbg, eaA, eaB, eaC, emask);
    node_attr_kernel<<<NN/256, 256, 0, stream>>>(eaA, eaB, eaC, emask, attr);
    convert_all_kernel<<<786432/256, 256, 0, stream>>>(Wm2, Wu1, Wu2, Wm1,
                                                       wm2t, wu1t, wu2t,
                                                       wzd_hi, wzd_lo, wzs_hi, wzs_lo);
    encoder_z_kernel<<<NN/32, 256, 0, stream>>>(types, attr, We, be,
                                                wzd_hi, wzd_lo, wzs_hi, wzs_lo,
                                                bm1, h, zs, zd);

    for (int l = 0; l < 2; ++l) {
        const float* wm1 = Wm1 + (size_t)l * DIN * HD;
        const float* wea = wm1 + (size_t)480 * HD;
        const short* w2t = wm2t + (size_t)l * 256 * 256;
        const float* bb2 = bm2 + l * HD;
        msg_mfma_kernel<KAK, 8><<<NA*KAK/64, 192, 0, stream>>>(
            zs, zd, nbr, eaA, eaB, eaC, emask, wea, w2t, bb2, agg, 0, 0);
        msg_gemm_kernel<<<EGE/48, 256, 0, stream>>>(zs, zd, nbg, eaA, eaB, eaC,
                                                    emask, wea, w2t, bb2, agg);
        if (l == 0) {
            update_z_kernel<true><<<NN/32, 256, 0, stream>>>(
                h, agg, attr,
                wu1t, bu1, wu2t, bu2,
                wzd_hi + 65536, wzd_lo + 65536, wzs_hi + 65536, wzs_lo + 65536,
                bm1 + HD, zs, zd);
        } else {
            update_z_kernel<false><<<NN/32, 256, 0, stream>>>(
                h, agg, attr,
                wu1t + (size_t)256 * 512, bu1 + HD, wu2t + (size_t)256 * 256, bu2 + HD,
                wzd_hi, wzd_lo, wzs_hi, wzs_lo,
                bm1, zs, zd);
        }
    }
    output_kernel<<<NG/4, 256, 0, stream>>>(h, Wo1, bo1, Wo2, bo2, out);
}

// Round 15
// 593.791 us; speedup vs baseline: 1.1276x; 1.1276x over previous
//
#include <hip/hip_runtime.h>
#include <math.h>

#define NA   1024
#define NGRID 4096
#define NB   2
#define NG   (NB*NGRID)   // 8192
#define NN   (NA+NG)      // 9216
#define KAK  8
#define KGK  24
#define EAE  (NA*KAK)     // 8192
#define EGE  (NG*KGK)     // 196608
#define ET   (EAE+EGE)    // 204800
#define HD   240
#define TT   16
#define DIN  489
#define CD   32
#define CUTF 8.0f

typedef __attribute__((ext_vector_type(8))) short short8;
typedef __attribute__((ext_vector_type(4))) short short4v;
typedef __attribute__((ext_vector_type(4))) float f32x4;
typedef __attribute__((ext_vector_type(4))) int i32x4;

__device__ __forceinline__ float silu_f(float x) {
    return x / (1.0f + __expf(-x));
}
__device__ __forceinline__ short f2bf(float x) {  // RNE f32->bf16
    unsigned u = __float_as_uint(x);
    unsigned r = (u + 0x7FFFu + ((u >> 16) & 1u)) >> 16;
    return (short)r;
}
__device__ __forceinline__ float bf2f(short s) {
    return __uint_as_float(((unsigned)(unsigned short)s) << 16);
}
__device__ __forceinline__ unsigned cvt_pk_bf16(float lo, float hi) {  // RNE, == f2bf pair
    unsigned r;
    asm("v_cvt_pk_bf16_f32 %0, %1, %2" : "=v"(r) : "v"(lo), "v"(hi));
    return r;
}

// ---------------- kNN (atoms + grid fused), wave-per-query, register top-K ----------------
template <int K>
__device__ __forceinline__ void wave_topk(unsigned long long key[8], int lane,
                                          int* __restrict__ outp) {
    unsigned long long lmin = key[0];
#pragma unroll
    for (int s = 1; s < 8; ++s) lmin = key[s] < lmin ? key[s] : lmin;
    int myout = -1;
    for (int t = 0; t < K; ++t) {
        unsigned long long m = lmin;
#pragma unroll
        for (int d = 1; d < 64; d <<= 1) {
            unsigned long long o = __shfl_xor(m, d);
            m = o < m ? o : m;
        }
        if (lane == t) myout = (int)(m & 1023u);
        if (m == lmin) {
#pragma unroll
            for (int s = 0; s < 8; ++s) if (key[s] == m) key[s] = ~0ull;
            lmin = key[0];
#pragma unroll
            for (int s = 1; s < 8; ++s) lmin = key[s] < lmin ? key[s] : lmin;
        }
    }
    if (lane < K) outp[lane] = myout;
}

__global__ __launch_bounds__(256) void knn_kernel(const float* __restrict__ pos,
                                                  int* __restrict__ nbr,
                                                  int* __restrict__ nbg) {
    __shared__ float sx[512], sy[512], sz[512];
    int tid = threadIdx.x;
    bool isAtom = blockIdx.x < (NA / 4);
    int q0 = isAtom ? blockIdx.x * 4 : (blockIdx.x - NA / 4) * 4;
    int pbase;
    if (isAtom) pbase = (q0 >= 512) ? 512 : 0;
    else        pbase = (q0 >= NGRID) ? 512 : 0;
    for (int j = tid; j < 512; j += 256) {
        sx[j] = pos[(pbase + j)*3 + 0];
        sy[j] = pos[(pbase + j)*3 + 1];
        sz[j] = pos[(pbase + j)*3 + 2];
    }
    __syncthreads();
    int lane = tid & 63;
    int qq = q0 + (tid >> 6);
    if (isAtom) {
        int i = qq;
        float px = sx[i - pbase], py = sy[i - pbase], pz = sz[i - pbase];
        unsigned long long key[8];
#pragma unroll
        for (int s = 0; s < 8; ++s) {
            int c = s * 64 + lane;
            int j = pbase + c;
            float dx = px - sx[c], dy = py - sy[c], dz = pz - sz[c];
            float d2 = __fadd_rn(__fadd_rn(__fmul_rn(dx,dx), __fmul_rn(dy,dy)), __fmul_rn(dz,dz));
            key[s] = ((unsigned long long)__float_as_uint(d2) << 10) | (unsigned)j;
            if (j == i) key[s] = ~0ull;
        }
        wave_topk<KAK>(key, lane, &nbr[i*KAK]);
    } else {
        int g = qq;
        int gi = g & (NGRID - 1);
        int ix = gi >> 8, iy = (gi >> 4) & 15, iz = gi & 15;
        float px = ((float)ix - 7.5f) * 1.5f;
        float py = ((float)iy - 7.5f) * 1.5f;
        float pz = ((float)iz - 7.5f) * 1.5f;
        unsigned long long key[8];
#pragma unroll
        for (int s = 0; s < 8; ++s) {
            int c = s * 64 + lane;
            int j = pbase + c;
            float dx = px - sx[c], dy = py - sy[c], dz = pz - sz[c];
            float d2 = __fadd_rn(__fadd_rn(__fmul_rn(dx,dx), __fmul_rn(dy,dy)), __fmul_rn(dz,dz));
            key[s] = ((unsigned long long)__float_as_uint(d2) << 10) | (unsigned)j;
        }
        wave_topk<KGK>(key, lane, &nbg[g*KGK]);
    }
}

// ---------------- edge features (sph * mask), split aligned storage ----------------
__global__ void edge_kernel(const float* __restrict__ pos, const int* __restrict__ nbr,
                            const int* __restrict__ nbg, float4* __restrict__ eaA,
                            float4* __restrict__ eaB, float* __restrict__ eaC,
                            float* __restrict__ emask) {
    int e = blockIdx.x * blockDim.x + threadIdx.x;
    if (e >= ET) return;
    int src; float dpx, dpy, dpz;
    if (e < EAE) {
        int d = e >> 3;
        src = nbr[e];
        dpx = pos[d*3]; dpy = pos[d*3+1]; dpz = pos[d*3+2];
    } else {
        int eg = e - EAE;
        src = nbg[eg];
        int gg = eg / KGK;
        int gi = gg % NGRID;
        int ix = gi >> 8, iy = (gi >> 4) & 15, iz = gi & 15;
        dpx = ((float)ix - 7.5f) * 1.5f;
        dpy = ((float)iy - 7.5f) * 1.5f;
        dpz = ((float)iz - 7.5f) * 1.5f;
    }
    float rx = pos[src*3] - dpx, ry = pos[src*3+1] - dpy, rz = pos[src*3+2] - dpz;
    float dist = sqrtf(rx*rx + ry*ry + rz*rz);
    float mask = (dist <= CUTF) ? 1.0f : 0.0f;
    float inv = 1.0f / fmaxf(dist, 1e-9f);
    float x = rx * inv, y = ry * inv, z = rz * inv;
    float s0 = 0.28209479177387814f;
    float s1 = 0.4886025119029199f * y;
    float s2 = 0.4886025119029199f * z;
    float s3 = 0.4886025119029199f * x;
    float s4 = 1.0925484305920792f * x * y;
    float s5 = 1.0925484305920792f * y * z;
    float s6 = 0.31539156525252005f * (3.0f * z * z - 1.0f);
    float s7 = 1.0925484305920792f * z * x;
    float s8 = 0.5462742152960396f * (x * x - y * y);
    eaA[e] = (float4){s0*mask, s1*mask, s2*mask, s3*mask};
    eaB[e] = (float4){s4*mask, s5*mask, s6*mask, s7*mask};
    eaC[e] = s8 * mask;
    emask[e] = mask;
}

// ---------------- node_attr (segment mean of ea) ----------------
__global__ void node_attr_kernel(const float4* __restrict__ eaA, const float4* __restrict__ eaB,
                                 const float* __restrict__ eaC, const float* __restrict__ emask,
                                 float* __restrict__ attr) {
    int n = blockIdx.x * blockDim.x + threadIdx.x;
    if (n >= NN) return;
    int K, e0;
    if (n < NA) { K = KAK; e0 = n * KAK; }
    else        { K = KGK; e0 = EAE + (n - NA) * KGK; }
    float s[9];
#pragma unroll
    for (int a = 0; a < 9; ++a) s[a] = 0.f;
    float cnt = 0.f;
    for (int k = 0; k < K; ++k) {
        cnt += emask[e0 + k];
        const float4 a0 = eaA[e0 + k];
        const float4 a1 = eaB[e0 + k];
        s[0] += a0.x; s[1] += a0.y; s[2] += a0.z; s[3] += a0.w;
        s[4] += a1.x; s[5] += a1.y; s[6] += a1.z; s[7] += a1.w;
        s[8] += eaC[e0 + k];
    }
    float invc = 1.0f / fmaxf(cnt, 1.0f);
    attr[n*9+0] = 1.0f;
#pragma unroll
    for (int a = 1; a < 9; ++a) attr[n*9+a] = s[a] * invc;
}

// ---------------- encoder: h = silu([feat|attr] @ We + be) ----------------
__global__ void encoder_kernel(const int* __restrict__ types, const float* __restrict__ attr,
                               const float* __restrict__ We, const float* __restrict__ be,
                               float* __restrict__ h) {
    int idx = blockIdx.x * blockDim.x + threadIdx.x;  // n*HD + j
    int n = idx / HD, j = idx % HD;
    float acc = be[j];
    if (n < NA) acc += We[types[n] * HD + j];
#pragma unroll
    for (int a = 0; a < 9; ++a) acc += attr[n*9+a] * We[(TT + a) * HD + j];
    h[idx] = silu_f(acc);
}

// ---------------- fused weight converter (all 5 jobs in one dispatch) ----------------
__global__ void convert_all_kernel(const float* __restrict__ Wm2, const float* __restrict__ Wu1,
                                   const float* __restrict__ Wu2, const float* __restrict__ Wm1,
                                   short* __restrict__ wm2t, short* __restrict__ wu1t,
                                   short* __restrict__ wu2t,
                                   short* __restrict__ wzd_hi, short* __restrict__ wzd_lo,
                                   short* __restrict__ wzs_hi, short* __restrict__ wzs_lo) {
    int idx = blockIdx.x * blockDim.x + threadIdx.x;
    if (idx < 131072) {                       // wm2t: [l][col 256][k 256], K=240
        int l = idx >> 16, rem = idx & 65535, col = rem >> 8, k = rem & 255;
        short v = 0;
        if (k < 240 && col < 240) v = f2bf(Wm2[(size_t)l*57600 + k*240 + col]);
        wm2t[idx] = v;
    } else if (idx < 393216) {                // wu1t: [l][col 256][k 512], K=489
        int i = idx - 131072;
        int l = i / 131072, rem = i % 131072, col = rem >> 9, k = rem & 511;
        short v = 0;
        if (k < DIN && col < 240) v = f2bf(Wu1[(size_t)l*DIN*240 + (size_t)k*240 + col]);
        wu1t[i] = v;
    } else if (idx < 524288) {                // wu2t: K=240
        int i = idx - 393216;
        int l = i >> 16, rem = i & 65535, col = rem >> 8, k = rem & 255;
        short v = 0;
        if (k < 240 && col < 240) v = f2bf(Wu2[(size_t)l*57600 + k*240 + col]);
        wu2t[i] = v;
    } else if (idx < 655360) {                // wzd hi/lo (Wm1 rows 240..479)
        int i = idx - 524288;
        int l = i >> 16, rem = i & 65535, col = rem >> 8, k = rem & 255;
        float v = 0.f;
        if (k < 240 && col < 240) v = Wm1[(size_t)l*DIN*HD + (size_t)(240 + k)*HD + col];
        short hh = f2bf(v);
        wzd_hi[i] = hh;
        wzd_lo[i] = f2bf(v - bf2f(hh));
    } else {                                  // wzs hi/lo (Wm1 rows 0..239)
        int i = idx - 655360;
        int l = i >> 16, rem = i & 65535, col = rem >> 8, k = rem & 255;
        float v = 0.f;
        if (k < 240 && col < 240) v = Wm1[(size_t)l*DIN*HD + (size_t)k*HD + col];
        short hh = f2bf(v);
        wzs_hi[i] = hh;
        wzs_lo[i] = f2bf(v - bf2f(hh));
    }
}

// ---------------- node Z via MFMA (hi/lo split, ~f32 accuracy) ----------------
__global__ __launch_bounds__(256) void node_z_mfma_kernel(
        const float* __restrict__ h,
        const short* __restrict__ wzd_hi, const short* __restrict__ wzd_lo,
        const short* __restrict__ wzs_hi, const short* __restrict__ wzs_lo,
        const float* __restrict__ bm1,
        float* __restrict__ Zs, float* __restrict__ Zd) {
    __shared__ __align__(16) short Ahi[32 * 256];
    __shared__ __align__(16) short Alo[32 * 256];
    int tid = threadIdx.x;
    int n0 = blockIdx.x * 32;

#pragma unroll
    for (int it = 0; it < 4; ++it) {
        int idx = it * 256 + tid;
        int row = idx >> 5, q = idx & 31;
        int j = q * 8;
        short8 ohi = {0,0,0,0,0,0,0,0}, olo = {0,0,0,0,0,0,0,0};
        if (j < 240) {
            const float4 a0 = *(const float4*)(h + (size_t)(n0 + row) * HD + j);
            const float4 a1 = *(const float4*)(h + (size_t)(n0 + row) * HD + j + 4);
            float v[8] = {a0.x, a0.y, a0.z, a0.w, a1.x, a1.y, a1.z, a1.w};
#pragma unroll
            for (int a = 0; a < 8; ++a) {
                short hh = f2bf(v[a]);
                ohi[a] = hh;
                olo[a] = f2bf(v[a] - bf2f(hh));
            }
        }
        int boff = row * 512 + ((q * 16) ^ ((row & 7) << 4));
        *(short8*)((char*)Ahi + boff) = ohi;
        *(short8*)((char*)Alo + boff) = olo;
    }
    __syncthreads();

    int wid = tid >> 6, lane = tid & 63;
    int mw = wid >> 1, nw = wid & 1;
    int lg = lane >> 4, lc = lane & 15;
    int col0 = nw * 128;
    int arow = (mw * 16 + lc) * 256;

    f32x4 acc[8];
#pragma unroll
    for (int nt = 0; nt < 8; ++nt) acc[nt] = (f32x4){0.f, 0.f, 0.f, 0.f};
    __builtin_amdgcn_s_setprio(1);
#pragma unroll
    for (int kc = 0; kc < 8; ++kc) {
        int aoff = arow + ((kc * 32 + lg * 8) ^ ((lc & 7) << 3));
        const short8 ahi = *(const short8*)&Ahi[aoff];
        const short8 alo = *(const short8*)&Alo[aoff];
#pragma unroll
        for (int nt = 0; nt < 8; ++nt) {
            size_t bo = (size_t)(col0 + nt*16 + lc) * 256 + kc*32 + lg*8;
            const short8 bhi = *(const short8*)(wzd_hi + bo);
            const short8 blo = *(const short8*)(wzd_lo + bo);
            acc[nt] = __builtin_amdgcn_mfma_f32_16x16x32_bf16(ahi, bhi, acc[nt], 0, 0, 0);
            acc[nt] = __builtin_amdgcn_mfma_f32_16x16x32_bf16(ahi, blo, acc[nt], 0, 0, 0);
            acc[nt] = __builtin_amdgcn_mfma_f32_16x16x32_bf16(alo, bhi, acc[nt], 0, 0, 0);
        }
    }
    __builtin_amdgcn_s_setprio(0);
#pragma unroll
    for (int nt = 0; nt < 8; ++nt) {
        int ncol = col0 + nt * 16 + lc;
        if (ncol < HD) {
            float bias = bm1[ncol];
            float vals[4] = {acc[nt].x, acc[nt].y, acc[nt].z, acc[nt].w};
#pragma unroll
            for (int r = 0; r < 4; ++r)
                Zd[(size_t)(n0 + mw*16 + lg*4 + r) * HD + ncol] = vals[r] + bias;
        }
    }

    if (n0 < NA) {
#pragma unroll
        for (int nt = 0; nt < 8; ++nt) acc[nt] = (f32x4){0.f, 0.f, 0.f, 0.f};
        __builtin_amdgcn_s_setprio(1);
#pragma unroll
        for (int kc = 0; kc < 8; ++kc) {
            int aoff = arow + ((kc * 32 + lg * 8) ^ ((lc & 7) << 3));
            const short8 ahi = *(const short8*)&Ahi[aoff];
            const short8 alo = *(const short8*)&Alo[aoff];
#pragma unroll
            for (int nt = 0; nt < 8; ++nt) {
                size_t bo = (size_t)(col0 + nt*16 + lc) * 256 + kc*32 + lg*8;
                const short8 bhi = *(const short8*)(wzs_hi + bo);
                const short8 blo = *(const short8*)(wzs_lo + bo);
                acc[nt] = __builtin_amdgcn_mfma_f32_16x16x32_bf16(ahi, bhi, acc[nt], 0, 0, 0);
                acc[nt] = __builtin_amdgcn_mfma_f32_16x16x32_bf16(ahi, blo, acc[nt], 0, 0, 0);
                acc[nt] = __builtin_amdgcn_mfma_f32_16x16x32_bf16(alo, bhi, acc[nt], 0, 0, 0);
            }
        }
        __builtin_amdgcn_s_setprio(0);
#pragma unroll
        for (int nt = 0; nt < 8; ++nt) {
            int ncol = col0 + nt * 16 + lc;
            if (ncol < HD) {
                float vals[4] = {acc[nt].x, acc[nt].y, acc[nt].z, acc[nt].w};
#pragma unroll
                for (int r = 0; r < 4; ++r)
                    Zs[(size_t)(n0 + mw*16 + lg*4 + r) * HD + ncol] = vals[r];
            }
        }
    }
}

// ---------------- fused grid-edge message MLP: 512 threads, 3 rows/thread assembly, 8-wave GEMM ----------------
__global__ __launch_bounds__(512) void msg_gemm_kernel(
        const float* __restrict__ Zs, const float* __restrict__ Zd,
        const int* __restrict__ nbg,
        const float4* __restrict__ eaA, const float4* __restrict__ eaB,
        const float* __restrict__ eaC,
        const float* __restrict__ emask, const float* __restrict__ Wea,
        const short* __restrict__ wm2t, const float* __restrict__ bm2,
        float* __restrict__ agg) {
    __shared__ __align__(16) short Abuf[48 * 256];   // 24KB, XOR-swizzled
    __shared__ __align__(16) float mkbuf[48];
    int tid = threadIdx.x;                            // 0..511
    int blk = blockIdx.x;
    int e0 = blk * 48;

    int q = tid & 31;        // col group (q<30 active; 30,31 write zero-pad)
    int rh = tid >> 5;       // 0..15 row-threads, 3 rows each
    float4 w0[9], w1[9];
    float4 zdA0, zdA1, zdB0, zdB1;
    int srcs[3];
    if (q < 30) {
        int j = q * 8;
#pragma unroll
        for (int a = 0; a < 9; ++a) {
            w0[a] = *(const float4*)(Wea + a * HD + j);
            w1[a] = *(const float4*)(Wea + a * HD + j + 4);
        }
#pragma unroll
        for (int r8 = 0; r8 < 3; ++r8) srcs[r8] = nbg[e0 + rh + r8 * 16];
        int dn0 = NA + blk * 2;
        zdA0 = *(const float4*)(Zd + (size_t)dn0 * HD + j);
        zdA1 = *(const float4*)(Zd + (size_t)dn0 * HD + j + 4);
        zdB0 = *(const float4*)(Zd + (size_t)(dn0 + 1) * HD + j);
        zdB1 = *(const float4*)(Zd + (size_t)(dn0 + 1) * HD + j + 4);
    }
    if (tid < 48) mkbuf[tid] = emask[EAE + e0 + tid];

#pragma unroll
    for (int r8 = 0; r8 < 3; ++r8) {
        int row = rh + r8 * 16;
        i32x4 oi = (i32x4){0, 0, 0, 0};
        if (q < 30) {
            int j = q * 8;
            int eg = e0 + row;
            int srcn = srcs[r8];
            const float4 zs0 = *(const float4*)(Zs + (size_t)srcn * HD + j);
            const float4 zs1 = *(const float4*)(Zs + (size_t)srcn * HD + j + 4);
            const float4 zd0 = (row < KGK) ? zdA0 : zdB0;
            const float4 zd1 = (row < KGK) ? zdA1 : zdB1;
            float s0 = zs0.x + zd0.x, s1 = zs0.y + zd0.y, s2 = zs0.z + zd0.z, s3 = zs0.w + zd0.w;
            float s4 = zs1.x + zd1.x, s5 = zs1.y + zd1.y, s6 = zs1.z + zd1.z, s7 = zs1.w + zd1.w;
            const float4 ea0 = eaA[EAE + eg];
            const float4 ea1 = eaB[EAE + eg];
            const float  ea8 = eaC[EAE + eg];
            float ev[9] = {ea0.x, ea0.y, ea0.z, ea0.w, ea1.x, ea1.y, ea1.z, ea1.w, ea8};
#pragma unroll
            for (int a = 0; a < 9; ++a) {
                float e = ev[a];
                s0 += e * w0[a].x; s1 += e * w0[a].y; s2 += e * w0[a].z; s3 += e * w0[a].w;
                s4 += e * w1[a].x; s5 += e * w1[a].y; s6 += e * w1[a].z; s7 += e * w1[a].w;
            }
            oi[0] = (int)cvt_pk_bf16(silu_f(s0), silu_f(s1));
            oi[1] = (int)cvt_pk_bf16(silu_f(s2), silu_f(s3));
            oi[2] = (int)cvt_pk_bf16(silu_f(s4), silu_f(s5));
            oi[3] = (int)cvt_pk_bf16(silu_f(s6), silu_f(s7));
        }
        *(i32x4*)((char*)Abuf + row * 512 + ((q * 16) ^ ((row & 7) << 4))) = oi;
    }
    __syncthreads();

    int wid = tid >> 6, lane = tid & 63;   // 8 waves
    int lg = lane >> 4, lc = lane & 15;
    int col0 = wid * 32;                   // 8 N-eighths of 32 cols

    f32x4 acc[3][2];
#pragma unroll
    for (int mt = 0; mt < 3; ++mt)
#pragma unroll
        for (int nt = 0; nt < 2; ++nt) acc[mt][nt] = (f32x4){0.f, 0.f, 0.f, 0.f};

    __builtin_amdgcn_s_setprio(1);
#pragma unroll
    for (int kc = 0; kc < 8; ++kc) {
        short8 af[3];
#pragma unroll
        for (int mt = 0; mt < 3; ++mt)
            af[mt] = *(const short8*)&Abuf[(mt*16 + lc) * 256 +
                                           ((kc*32 + lg*8) ^ ((lc & 7) << 3))];
#pragma unroll
        for (int nt = 0; nt < 2; ++nt) {
            const short8 bf = *(const short8*)(wm2t + (size_t)(col0 + nt*16 + lc) * 256 + kc*32 + lg*8);
#pragma unroll
            for (int mt = 0; mt < 3; ++mt)
                acc[mt][nt] = __builtin_amdgcn_mfma_f32_16x16x32_bf16(af[mt], bf, acc[mt][nt], 0, 0, 0);
        }
    }
    __builtin_amdgcn_s_setprio(0);

#pragma unroll
    for (int nt = 0; nt < 2; ++nt) {
        int ncol = col0 + nt * 16 + lc;
        float bias = (ncol < HD) ? bm2[ncol] : 0.f;
        float p[3];
#pragma unroll
        for (int mt = 0; mt < 3; ++mt) {
            const float4 mkv = *(const float4*)&mkbuf[mt*16 + lg*4];
            float t0 = silu_f(acc[mt][nt].x + bias) * mkv.x;
            float t1 = silu_f(acc[mt][nt].y + bias) * mkv.y;
            float t2 = silu_f(acc[mt][nt].z + bias) * mkv.z;
            float t3 = silu_f(acc[mt][nt].w + bias) * mkv.w;
            p[mt] = (t0 + t1) + (t2 + t3);
        }
        float v0 = p[0] + ((lg < 2) ? p[1] : 0.f);
        float v1 = ((lg >= 2) ? p[1] : 0.f) + p[2];
        v0 += __shfl_xor(v0, 16); v0 += __shfl_xor(v0, 32);
        v1 += __shfl_xor(v1, 16); v1 += __shfl_xor(v1, 32);
        if (ncol < HD) {
            int node = NA + blk * 2;
            if (lane < 16)      agg[(size_t)(node + 0) * HD + ncol] = v0;
            else if (lane < 32) agg[(size_t)(node + 1) * HD + ncol] = v1;
        }
    }
}

// ---------------- fused message MLP for ATOM edges ----------------
template <int KE, int NPB>
__global__ __launch_bounds__(192) void msg_mfma_kernel(
        const float* __restrict__ Zs, const float* __restrict__ Zd,
        const int* __restrict__ nbrList,
        const float4* __restrict__ eaA, const float4* __restrict__ eaB,
        const float* __restrict__ eaC,
        const float* __restrict__ emask, const float* __restrict__ Wea,
        const short* __restrict__ wm2t, const float* __restrict__ bm2,
        float* __restrict__ agg, int dstBase, int edgeBase) {
    constexpr int ROWS = KE * NPB;
    constexpr int MT = ROWS / 16;
    __shared__ __align__(16) short Abuf[ROWS * 264];
    __shared__ __align__(16) float mkbuf[ROWS];

    int tid = threadIdx.x;
    int b = blockIdx.x;
    int e0 = edgeBase + b * ROWS;

    if (tid < ROWS) mkbuf[tid] = emask[e0 + tid];
    for (int idx = tid; idx < ROWS * 24; idx += 192) {
        int r = idx / 24;
        Abuf[r * 264 + 240 + (idx % 24)] = 0;
    }
    for (int idx = tid; idx < ROWS * 60; idx += 192) {
        int row = idx / 60;
        int j = (idx % 60) * 4;
        int srcn = nbrList[b * ROWS + row];
        int dstn = dstBase + b * NPB + row / KE;
        const float4 zs = *(const float4*)(Zs + (size_t)srcn * HD + j);
        const float4 zd = *(const float4*)(Zd + (size_t)dstn * HD + j);
        float s0 = zs.x + zd.x, s1 = zs.y + zd.y, s2 = zs.z + zd.z, s3 = zs.w + zd.w;
        const float4 ea0 = eaA[e0 + row];
        const float4 ea1 = eaB[e0 + row];
        const float  ea8 = eaC[e0 + row];
        float ev[9] = {ea0.x, ea0.y, ea0.z, ea0.w, ea1.x, ea1.y, ea1.z, ea1.w, ea8};
#pragma unroll
        for (int a = 0; a < 9; ++a) {
            float e = ev[a];
            const float4 w = *(const float4*)(Wea + a * HD + j);
            s0 += e * w.x; s1 += e * w.y; s2 += e * w.z; s3 += e * w.w;
        }
        short4v o;
        o.x = f2bf(silu_f(s0)); o.y = f2bf(silu_f(s1));
        o.z = f2bf(silu_f(s2)); o.w = f2bf(silu_f(s3));
        *(short4v*)&Abuf[row * 264 + j] = o;
    }
    __syncthreads();

    int w = tid / 64, lane = tid % 64;
    int lg = lane >> 4, lc = lane & 15;
    int wcol0 = w * 80;

    f32x4 acc[MT][5];
#pragma unroll
    for (int mt = 0; mt < MT; ++mt)
#pragma unroll
        for (int nt = 0; nt < 5; ++nt) acc[mt][nt] = (f32x4){0.f, 0.f, 0.f, 0.f};

#pragma unroll
    for (int kc = 0; kc < 8; ++kc) {
        short8 af[MT];
#pragma unroll
        for (int mt = 0; mt < MT; ++mt)
            af[mt] = *(const short8*)&Abuf[(mt * 16 + lc) * 264 + kc * 32 + lg * 8];
#pragma unroll
        for (int nt = 0; nt < 5; ++nt) {
            const short8 bf = *(const short8*)(wm2t + (size_t)(wcol0 + nt * 16 + lc) * 256 + kc * 32 + lg * 8);
#pragma unroll
            for (int mt = 0; mt < MT; ++mt)
                acc[mt][nt] = __builtin_amdgcn_mfma_f32_16x16x32_bf16(af[mt], bf, acc[mt][nt], 0, 0, 0);
        }
    }

#pragma unroll
    for (int nt = 0; nt < 5; ++nt) {
        int ncol = wcol0 + nt * 16 + lc;
        float bias = bm2[ncol];
        float p[MT];
#pragma unroll
        for (int mt = 0; mt < MT; ++mt) {
            const float4 mkv = *(const float4*)&mkbuf[mt * 16 + lg * 4];
            float t0 = silu_f(acc[mt][nt].x + bias) * mkv.x;
            float t1 = silu_f(acc[mt][nt].y + bias) * mkv.y;
            float t2 = silu_f(acc[mt][nt].z + bias) * mkv.z;
            float t3 = silu_f(acc[mt][nt].w + bias) * mkv.w;
            p[mt] = (t0 + t1) + (t2 + t3);
        }
#pragma unroll
        for (int mt = 0; mt < MT; ++mt) {
            float v = p[mt];
            v += __shfl_xor(v, 16);
            if (lane < 16)
                agg[(size_t)(dstBase + b * (2 * MT) + 2 * mt + 0) * HD + ncol] = v;
            else if (lane >= 32 && lane < 48)
                agg[(size_t)(dstBase + b * (2 * MT) + 2 * mt + 1) * HD + ncol] = v;
        }
    }
}

// ---------------- MFMA node update: h += silu(silu(ui@Wu1+bu1)@Wu2+bu2), ui=[h|agg|attr] ----------------
__global__ __launch_bounds__(256) void update_mfma_kernel(
        float* __restrict__ h, const float* __restrict__ agg,
        const float* __restrict__ attr,
        const short* __restrict__ wu1t, const float* __restrict__ bu1,
        const short* __restrict__ wu2t, const float* __restrict__ bu2) {
    __shared__ __align__(16) short Abuf[32 * 512];
    __shared__ __align__(16) short Ubuf[32 * 256];
    int tid = threadIdx.x;
    int n0 = blockIdx.x * 32;

#pragma unroll
    for (int it = 0; it < 8; ++it) {
        int idx = it * 256 + tid;
        int row = idx >> 6, q = idx & 63;
        int j = q * 8;
        int n = n0 + row;
        short8 o = {0,0,0,0,0,0,0,0};
        if (j < 240) {
            const float4 a0 = *(const float4*)(h + (size_t)n * HD + j);
            const float4 a1 = *(const float4*)(h + (size_t)n * HD + j + 4);
            o[0]=f2bf(a0.x); o[1]=f2bf(a0.y); o[2]=f2bf(a0.z); o[3]=f2bf(a0.w);
            o[4]=f2bf(a1.x); o[5]=f2bf(a1.y); o[6]=f2bf(a1.z); o[7]=f2bf(a1.w);
        } else if (j < 480) {
            const float4 a0 = *(const float4*)(agg + (size_t)n * HD + (j - 240));
            const float4 a1 = *(const float4*)(agg + (size_t)n * HD + (j - 240) + 4);
            o[0]=f2bf(a0.x); o[1]=f2bf(a0.y); o[2]=f2bf(a0.z); o[3]=f2bf(a0.w);
            o[4]=f2bf(a1.x); o[5]=f2bf(a1.y); o[6]=f2bf(a1.z); o[7]=f2bf(a1.w);
        } else if (j == 480) {
#pragma unroll
            for (int a = 0; a < 8; ++a) o[a] = f2bf(attr[n*9 + a]);
        } else if (j == 488) {
            o[0] = f2bf(attr[n*9 + 8]);
        }
        *(short8*)((char*)Abuf + row * 1024 + ((q * 16) ^ ((row & 7) << 4))) = o;
    }
    __syncthreads();

    int wid = tid >> 6, lane = tid & 63;
    int mw = wid >> 1, nw = wid & 1;
    int lg = lane >> 4, lc = lane & 15;
    int col0 = nw * 128;

    f32x4 acc[8];
#pragma unroll
    for (int nt = 0; nt < 8; ++nt) acc[nt] = (f32x4){0.f, 0.f, 0.f, 0.f};
    __builtin_amdgcn_s_setprio(1);
#pragma unroll
    for (int kc = 0; kc < 16; ++kc) {
        const short8 af = *(const short8*)((char*)Abuf + (mw*16 + lc) * 1024 +
                                           ((kc*64 + lg*16) ^ ((lc & 7) << 4)));
#pragma unroll
        for (int nt = 0; nt < 8; ++nt) {
            const short8 bf = *(const short8*)(wu1t + (size_t)(col0 + nt*16 + lc) * 512 + kc*32 + lg*8);
            acc[nt] = __builtin_amdgcn_mfma_f32_16x16x32_bf16(af, bf, acc[nt], 0, 0, 0);
        }
    }
    __builtin_amdgcn_s_setprio(0);
#pragma unroll
    for (int nt = 0; nt < 8; ++nt) {
        int ncol = col0 + nt * 16 + lc;
        float bias = (ncol < HD) ? bu1[ncol] : 0.f;
        float vals[4] = {acc[nt].x, acc[nt].y, acc[nt].z, acc[nt].w};
#pragma unroll
        for (int r = 0; r < 4; ++r) {
            int row = mw*16 + lg*4 + r;
            *(short*)((char*)Ubuf + row * 512 + ((ncol * 2) ^ ((row & 7) << 4))) =
                f2bf(silu_f(vals[r] + bias));
        }
    }
    __syncthreads();

    f32x4 acc2[8];
#pragma unroll
    for (int nt = 0; nt < 8; ++nt) acc2[nt] = (f32x4){0.f, 0.f, 0.f, 0.f};
    __builtin_amdgcn_s_setprio(1);
#pragma unroll
    for (int kc = 0; kc < 8; ++kc) {
        const short8 af = *(const short8*)((char*)Ubuf + (mw*16 + lc) * 512 +
                                           ((kc*64 + lg*16) ^ ((lc & 7) << 4)));
#pragma unroll
        for (int nt = 0; nt < 8; ++nt) {
            const short8 bf = *(const short8*)(wu2t + (size_t)(col0 + nt*16 + lc) * 256 + kc*32 + lg*8);
            acc2[nt] = __builtin_amdgcn_mfma_f32_16x16x32_bf16(af, bf, acc2[nt], 0, 0, 0);
        }
    }
    __builtin_amdgcn_s_setprio(0);
#pragma unroll
    for (int nt = 0; nt < 8; ++nt) {
        int ncol = col0 + nt * 16 + lc;
        if (ncol < HD) {
            float bias = bu2[ncol];
            float vals[4] = {acc2[nt].x, acc2[nt].y, acc2[nt].z, acc2[nt].w};
#pragma unroll
            for (int r = 0; r < 4; ++r) {
                int row = mw*16 + lg*4 + r;
                size_t hi = (size_t)(n0 + row) * HD + ncol;
                h[hi] += silu_f(vals[r] + bias);
            }
        }
    }
}

// ---------------- readout (grid nodes only) ----------------
__global__ void output_kernel(const float* __restrict__ h,
                              const float* __restrict__ Wo1, const float* __restrict__ bo1,
                              const float* __restrict__ Wo2, const float* __restrict__ bo2,
                              float* __restrict__ out) {
    const int NBT = 4;
    __shared__ float hr[NBT][HD];
    __shared__ float o1[NBT][HD];
    int tid = threadIdx.x;
    int g0 = blockIdx.x * NBT;
    for (int idx = tid; idx < NBT * HD; idx += 256) {
        int k = idx / HD, i = idx % HD;
        hr[k][i] = h[(size_t)(NA + g0 + k) * HD + i];
    }
    __syncthreads();
    int j = tid;
    if (j < HD) {
        float acc[NBT] = {0.f, 0.f, 0.f, 0.f};
        for (int i4 = 0; i4 < 60; ++i4) {
            int i = 4 * i4;
            float w0 = Wo1[(i+0)*HD+j], w1 = Wo1[(i+1)*HD+j];
            float w2 = Wo1[(i+2)*HD+j], w3 = Wo1[(i+3)*HD+j];
#pragma unroll
            for (int k = 0; k < NBT; ++k) {
                const float4 a = *reinterpret_cast<const float4*>(&hr[k][i]);
                acc[k] += a.x*w0 + a.y*w1 + a.z*w2 + a.w*w3;
            }
        }
        float bb = bo1[j];
#pragma unroll
        for (int k = 0; k < NBT; ++k) o1[k][j] = silu_f(acc[k] + bb);
    }
    __syncthreads();
    if (tid < NBT * CD) {
        int k = tid >> 5, c = tid & 31;
        float acc = bo2[c];
        for (int i = 0; i < HD; ++i) acc += o1[k][i] * Wo2[i*CD + c];
        out[(size_t)(g0 + k) * CD + c] = acc;
    }
}

extern "C" void kernel_launch(void* const* d_in, const int* in_sizes, int n_in,
                              void* d_out, int out_size, void* d_ws, size_t ws_size,
                              hipStream_t stream) {
    (void)in_sizes; (void)n_in; (void)out_size; (void)ws_size;
    const float* pos   = (const float*)d_in[0];
    const int*   types = (const int*)d_in[1];
    const int*   batch = (const int*)d_in[2];
    (void)batch;
    const float* We    = (const float*)d_in[3];
    const float* be    = (const float*)d_in[4];
    const float* Wm1   = (const float*)d_in[5];
    const float* bm1   = (const float*)d_in[6];
    const float* Wm2   = (const float*)d_in[7];
    const float* bm2   = (const float*)d_in[8];
    const float* Wu1   = (const float*)d_in[9];
    const float* bu1   = (const float*)d_in[10];
    const float* Wu2   = (const float*)d_in[11];
    const float* bu2   = (const float*)d_in[12];
    const float* Wo1   = (const float*)d_in[13];
    const float* bo1   = (const float*)d_in[14];
    const float* Wo2   = (const float*)d_in[15];
    const float* bo2   = (const float*)d_in[16];
    float* out = (float*)d_out;

    char* ws = (char*)d_ws;
    size_t off = 0;
    auto take = [&](size_t bytes) -> char* {
        char* p = ws + off;
        off = (off + bytes + 255) & ~(size_t)255;
        return p;
    };
    int*    nbr    = (int*)take((size_t)EAE * 4);
    int*    nbg    = (int*)take((size_t)EGE * 4);
    float4* eaA    = (float4*)take((size_t)ET * 16);
    float4* eaB    = (float4*)take((size_t)ET * 16);
    float*  eaC    = (float*)take((size_t)ET * 4);
    float*  emask  = (float*)take((size_t)ET * 4);
    float*  attr   = (float*)take((size_t)NN * 9 * 4);
    float*  h      = (float*)take((size_t)NN * HD * 4);
    float*  agg    = (float*)take((size_t)NN * HD * 4);
    float*  zs     = (float*)take((size_t)NA * HD * 4);
    float*  zd     = (float*)take((size_t)NN * HD * 4);
    short*  wm2t   = (short*)take((size_t)2 * 256 * 256 * 2);
    short*  wu1t   = (short*)take((size_t)2 * 256 * 512 * 2);
    short*  wu2t   = (short*)take((size_t)2 * 256 * 256 * 2);
    short*  wzd_hi = (short*)take((size_t)2 * 256 * 256 * 2);
    short*  wzd_lo = (short*)take((size_t)2 * 256 * 256 * 2);
    short*  wzs_hi = (short*)take((size_t)2 * 256 * 256 * 2);
    short*  wzs_lo = (short*)take((size_t)2 * 256 * 256 * 2);

    knn_kernel<<<NA/4 + NG/4, 256, 0, stream>>>(pos, nbr, nbg);
    edge_kernel<<<ET/256, 256, 0, stream>>>(pos, nbr, nbg, eaA, eaB, eaC, emask);
    node_attr_kernel<<<NN/256, 256, 0, stream>>>(eaA, eaB, eaC, emask, attr);
    encoder_kernel<<<(NN*HD)/256, 256, 0, stream>>>(types, attr, We, be, h);
    convert_all_kernel<<<786432/256, 256, 0, stream>>>(Wm2, Wu1, Wu2, Wm1,
                                                       wm2t, wu1t, wu2t,
                                                       wzd_hi, wzd_lo, wzs_hi, wzs_lo);

    for (int l = 0; l < 2; ++l) {
        const float* wm1 = Wm1 + (size_t)l * DIN * HD;
        const float* wea = wm1 + (size_t)480 * HD;
        const short* w2t = wm2t + (size_t)l * 256 * 256;
        const float* bb2 = bm2 + l * HD;
        node_z_mfma_kernel<<<NN/32, 256, 0, stream>>>(
            h,
            wzd_hi + (size_t)l * 65536, wzd_lo + (size_t)l * 65536,
            wzs_hi + (size_t)l * 65536, wzs_lo + (size_t)l * 65536,
            bm1 + l * HD, zs, zd);
        msg_mfma_kernel<KAK, 8><<<NA*KAK/64, 192, 0, stream>>>(
            zs, zd, nbr, eaA, eaB, eaC, emask, wea, w2t, bb2, agg, 0, 0);
        msg_gemm_kernel<<<EGE/48, 512, 0, stream>>>(zs, zd, nbg, eaA, eaB, eaC,
                                                    emask, wea, w2t, bb2, agg);
        update_mfma_kernel<<<NN/32, 256, 0, stream>>>(
            h, agg, attr,
            wu1t + (size_t)l * 256 * 512, bu1 + l * HD,
            wu2t + (size_t)l * 256 * 256, bu2 + l * HD);
    }
    output_kernel<<<NG/4, 256, 0, stream>>>(h, Wo1, bo1, Wo2, bo2, out);
}

// Round 16
// 572.969 us; speedup vs baseline: 1.1686x; 1.0363x over previous
//
#include <hip/hip_runtime.h>
#include <math.h>

#define NA   1024
#define NGRID 4096
#define NB   2
#define NG   (NB*NGRID)   // 8192
#define NN   (NA+NG)      // 9216
#define KAK  8
#define KGK  24
#define EAE  (NA*KAK)     // 8192
#define EGE  (NG*KGK)     // 196608
#define ET   (EAE+EGE)    // 204800
#define HD   240
#define TT   16
#define DIN  489
#define CD   32
#define CUTF 8.0f

typedef __attribute__((ext_vector_type(8))) short short8;
typedef __attribute__((ext_vector_type(4))) short short4v;
typedef __attribute__((ext_vector_type(4))) float f32x4;
typedef __attribute__((ext_vector_type(4))) int i32x4;

__device__ __forceinline__ float silu_f(float x) {
    return x / (1.0f + __expf(-x));
}
__device__ __forceinline__ short f2bf(float x) {  // RNE f32->bf16
    unsigned u = __float_as_uint(x);
    unsigned r = (u + 0x7FFFu + ((u >> 16) & 1u)) >> 16;
    return (short)r;
}
__device__ __forceinline__ float bf2f(short s) {
    return __uint_as_float(((unsigned)(unsigned short)s) << 16);
}
__device__ __forceinline__ unsigned cvt_pk_bf16(float lo, float hi) {  // RNE, == f2bf pair
    unsigned r;
    asm("v_cvt_pk_bf16_f32 %0, %1, %2" : "=v"(r) : "v"(lo), "v"(hi));
    return r;
}

// ---------------- kNN (atoms + grid fused), wave-per-query, register top-K ----------------
template <int K>
__device__ __forceinline__ void wave_topk(unsigned long long key[8], int lane,
                                          int* __restrict__ outp) {
    unsigned long long lmin = key[0];
#pragma unroll
    for (int s = 1; s < 8; ++s) lmin = key[s] < lmin ? key[s] : lmin;
    int myout = -1;
    for (int t = 0; t < K; ++t) {
        unsigned long long m = lmin;
#pragma unroll
        for (int d = 1; d < 64; d <<= 1) {
            unsigned long long o = __shfl_xor(m, d);
            m = o < m ? o : m;
        }
        if (lane == t) myout = (int)(m & 1023u);
        if (m == lmin) {
#pragma unroll
            for (int s = 0; s < 8; ++s) if (key[s] == m) key[s] = ~0ull;
            lmin = key[0];
#pragma unroll
            for (int s = 1; s < 8; ++s) lmin = key[s] < lmin ? key[s] : lmin;
        }
    }
    if (lane < K) outp[lane] = myout;
}

__global__ __launch_bounds__(256) void knn_kernel(const float* __restrict__ pos,
                                                  int* __restrict__ nbr,
                                                  int* __restrict__ nbg) {
    __shared__ float sx[512], sy[512], sz[512];
    int tid = threadIdx.x;
    bool isAtom = blockIdx.x < (NA / 4);
    int q0 = isAtom ? blockIdx.x * 4 : (blockIdx.x - NA / 4) * 4;
    int pbase;
    if (isAtom) pbase = (q0 >= 512) ? 512 : 0;
    else        pbase = (q0 >= NGRID) ? 512 : 0;
    for (int j = tid; j < 512; j += 256) {
        sx[j] = pos[(pbase + j)*3 + 0];
        sy[j] = pos[(pbase + j)*3 + 1];
        sz[j] = pos[(pbase + j)*3 + 2];
    }
    __syncthreads();
    int lane = tid & 63;
    int qq = q0 + (tid >> 6);
    if (isAtom) {
        int i = qq;
        float px = sx[i - pbase], py = sy[i - pbase], pz = sz[i - pbase];
        unsigned long long key[8];
#pragma unroll
        for (int s = 0; s < 8; ++s) {
            int c = s * 64 + lane;
            int j = pbase + c;
            float dx = px - sx[c], dy = py - sy[c], dz = pz - sz[c];
            float d2 = __fadd_rn(__fadd_rn(__fmul_rn(dx,dx), __fmul_rn(dy,dy)), __fmul_rn(dz,dz));
            key[s] = ((unsigned long long)__float_as_uint(d2) << 10) | (unsigned)j;
            if (j == i) key[s] = ~0ull;
        }
        wave_topk<KAK>(key, lane, &nbr[i*KAK]);
    } else {
        int g = qq;
        int gi = g & (NGRID - 1);
        int ix = gi >> 8, iy = (gi >> 4) & 15, iz = gi & 15;
        float px = ((float)ix - 7.5f) * 1.5f;
        float py = ((float)iy - 7.5f) * 1.5f;
        float pz = ((float)iz - 7.5f) * 1.5f;
        unsigned long long key[8];
#pragma unroll
        for (int s = 0; s < 8; ++s) {
            int c = s * 64 + lane;
            int j = pbase + c;
            float dx = px - sx[c], dy = py - sy[c], dz = pz - sz[c];
            float d2 = __fadd_rn(__fadd_rn(__fmul_rn(dx,dx), __fmul_rn(dy,dy)), __fmul_rn(dz,dz));
            key[s] = ((unsigned long long)__float_as_uint(d2) << 10) | (unsigned)j;
        }
        wave_topk<KGK>(key, lane, &nbg[g*KGK]);
    }
}

// ---------------- edge features (sph * mask), split aligned storage ----------------
__global__ void edge_kernel(const float* __restrict__ pos, const int* __restrict__ nbr,
                            const int* __restrict__ nbg, float4* __restrict__ eaA,
                            float4* __restrict__ eaB, float* __restrict__ eaC,
                            float* __restrict__ emask) {
    int e = blockIdx.x * blockDim.x + threadIdx.x;
    if (e >= ET) return;
    int src; float dpx, dpy, dpz;
    if (e < EAE) {
        int d = e >> 3;
        src = nbr[e];
        dpx = pos[d*3]; dpy = pos[d*3+1]; dpz = pos[d*3+2];
    } else {
        int eg = e - EAE;
        src = nbg[eg];
        int gg = eg / KGK;
        int gi = gg % NGRID;
        int ix = gi >> 8, iy = (gi >> 4) & 15, iz = gi & 15;
        dpx = ((float)ix - 7.5f) * 1.5f;
        dpy = ((float)iy - 7.5f) * 1.5f;
        dpz = ((float)iz - 7.5f) * 1.5f;
    }
    float rx = pos[src*3] - dpx, ry = pos[src*3+1] - dpy, rz = pos[src*3+2] - dpz;
    float dist = sqrtf(rx*rx + ry*ry + rz*rz);
    float mask = (dist <= CUTF) ? 1.0f : 0.0f;
    float inv = 1.0f / fmaxf(dist, 1e-9f);
    float x = rx * inv, y = ry * inv, z = rz * inv;
    float s0 = 0.28209479177387814f;
    float s1 = 0.4886025119029199f * y;
    float s2 = 0.4886025119029199f * z;
    float s3 = 0.4886025119029199f * x;
    float s4 = 1.0925484305920792f * x * y;
    float s5 = 1.0925484305920792f * y * z;
    float s6 = 0.31539156525252005f * (3.0f * z * z - 1.0f);
    float s7 = 1.0925484305920792f * z * x;
    float s8 = 0.5462742152960396f * (x * x - y * y);
    eaA[e] = (float4){s0*mask, s1*mask, s2*mask, s3*mask};
    eaB[e] = (float4){s4*mask, s5*mask, s6*mask, s7*mask};
    eaC[e] = s8 * mask;
    emask[e] = mask;
}

// ---------------- node_attr (segment mean of ea) ----------------
__global__ void node_attr_kernel(const float4* __restrict__ eaA, const float4* __restrict__ eaB,
                                 const float* __restrict__ eaC, const float* __restrict__ emask,
                                 float* __restrict__ attr) {
    int n = blockIdx.x * blockDim.x + threadIdx.x;
    if (n >= NN) return;
    int K, e0;
    if (n < NA) { K = KAK; e0 = n * KAK; }
    else        { K = KGK; e0 = EAE + (n - NA) * KGK; }
    float s[9];
#pragma unroll
    for (int a = 0; a < 9; ++a) s[a] = 0.f;
    float cnt = 0.f;
    for (int k = 0; k < K; ++k) {
        cnt += emask[e0 + k];
        const float4 a0 = eaA[e0 + k];
        const float4 a1 = eaB[e0 + k];
        s[0] += a0.x; s[1] += a0.y; s[2] += a0.z; s[3] += a0.w;
        s[4] += a1.x; s[5] += a1.y; s[6] += a1.z; s[7] += a1.w;
        s[8] += eaC[e0 + k];
    }
    float invc = 1.0f / fmaxf(cnt, 1.0f);
    attr[n*9+0] = 1.0f;
#pragma unroll
    for (int a = 1; a < 9; ++a) attr[n*9+a] = s[a] * invc;
}

// ---------------- encoder: h = silu([feat|attr] @ We + be) ----------------
__global__ void encoder_kernel(const int* __restrict__ types, const float* __restrict__ attr,
                               const float* __restrict__ We, const float* __restrict__ be,
                               float* __restrict__ h) {
    int idx = blockIdx.x * blockDim.x + threadIdx.x;  // n*HD + j
    int n = idx / HD, j = idx % HD;
    float acc = be[j];
    if (n < NA) acc += We[types[n] * HD + j];
#pragma unroll
    for (int a = 0; a < 9; ++a) acc += attr[n*9+a] * We[(TT + a) * HD + j];
    h[idx] = silu_f(acc);
}

// ---------------- fused weight converter (all 5 jobs in one dispatch) ----------------
__global__ void convert_all_kernel(const float* __restrict__ Wm2, const float* __restrict__ Wu1,
                                   const float* __restrict__ Wu2, const float* __restrict__ Wm1,
                                   short* __restrict__ wm2t, short* __restrict__ wu1t,
                                   short* __restrict__ wu2t,
                                   short* __restrict__ wzd_hi, short* __restrict__ wzd_lo,
                                   short* __restrict__ wzs_hi, short* __restrict__ wzs_lo) {
    int idx = blockIdx.x * blockDim.x + threadIdx.x;
    if (idx < 131072) {                       // wm2t: [l][col 256][k 256], K=240
        int l = idx >> 16, rem = idx & 65535, col = rem >> 8, k = rem & 255;
        short v = 0;
        if (k < 240 && col < 240) v = f2bf(Wm2[(size_t)l*57600 + k*240 + col]);
        wm2t[idx] = v;
    } else if (idx < 393216) {                // wu1t: [l][col 256][k 512], K=489
        int i = idx - 131072;
        int l = i / 131072, rem = i % 131072, col = rem >> 9, k = rem & 511;
        short v = 0;
        if (k < DIN && col < 240) v = f2bf(Wu1[(size_t)l*DIN*240 + (size_t)k*240 + col]);
        wu1t[i] = v;
    } else if (idx < 524288) {                // wu2t: K=240
        int i = idx - 393216;
        int l = i >> 16, rem = i & 65535, col = rem >> 8, k = rem & 255;
        short v = 0;
        if (k < 240 && col < 240) v = f2bf(Wu2[(size_t)l*57600 + k*240 + col]);
        wu2t[i] = v;
    } else if (idx < 655360) {                // wzd hi/lo (Wm1 rows 240..479)
        int i = idx - 524288;
        int l = i >> 16, rem = i & 65535, col = rem >> 8, k = rem & 255;
        float v = 0.f;
        if (k < 240 && col < 240) v = Wm1[(size_t)l*DIN*HD + (size_t)(240 + k)*HD + col];
        short hh = f2bf(v);
        wzd_hi[i] = hh;
        wzd_lo[i] = f2bf(v - bf2f(hh));
    } else {                                  // wzs hi/lo (Wm1 rows 0..239)
        int i = idx - 655360;
        int l = i >> 16, rem = i & 65535, col = rem >> 8, k = rem & 255;
        float v = 0.f;
        if (k < 240 && col < 240) v = Wm1[(size_t)l*DIN*HD + (size_t)k*HD + col];
        short hh = f2bf(v);
        wzs_hi[i] = hh;
        wzs_lo[i] = f2bf(v - bf2f(hh));
    }
}

// ---------------- node Z via MFMA (hi/lo split), 512 threads / 8 waves ----------------
__global__ __launch_bounds__(512) void node_z_mfma_kernel(
        const float* __restrict__ h,
        const short* __restrict__ wzd_hi, const short* __restrict__ wzd_lo,
        const short* __restrict__ wzs_hi, const short* __restrict__ wzs_lo,
        const float* __restrict__ bm1,
        float* __restrict__ Zs, float* __restrict__ Zd) {
    __shared__ __align__(16) short Ahi[32 * 256];
    __shared__ __align__(16) short Alo[32 * 256];
    int tid = threadIdx.x;
    int n0 = blockIdx.x * 32;

#pragma unroll
    for (int it = 0; it < 2; ++it) {
        int idx = it * 512 + tid;
        int row = idx >> 5, q = idx & 31;
        int j = q * 8;
        short8 ohi = {0,0,0,0,0,0,0,0}, olo = {0,0,0,0,0,0,0,0};
        if (j < 240) {
            const float4 a0 = *(const float4*)(h + (size_t)(n0 + row) * HD + j);
            const float4 a1 = *(const float4*)(h + (size_t)(n0 + row) * HD + j + 4);
            float v[8] = {a0.x, a0.y, a0.z, a0.w, a1.x, a1.y, a1.z, a1.w};
#pragma unroll
            for (int a = 0; a < 8; ++a) {
                short hh = f2bf(v[a]);
                ohi[a] = hh;
                olo[a] = f2bf(v[a] - bf2f(hh));
            }
        }
        int boff = row * 512 + ((q * 16) ^ ((row & 7) << 4));
        *(short8*)((char*)Ahi + boff) = ohi;
        *(short8*)((char*)Alo + boff) = olo;
    }
    __syncthreads();

    int wid = tid >> 6, lane = tid & 63;     // 8 waves
    int mw = wid >> 2, nw = wid & 3;          // 2 M-slices x 4 N-quarters
    int lg = lane >> 4, lc = lane & 15;
    int col0 = nw * 64;
    int arow = (mw * 16 + lc) * 256;

    f32x4 acc[4];
#pragma unroll
    for (int nt = 0; nt < 4; ++nt) acc[nt] = (f32x4){0.f, 0.f, 0.f, 0.f};
    __builtin_amdgcn_s_setprio(1);
#pragma unroll
    for (int kc = 0; kc < 8; ++kc) {
        int aoff = arow + ((kc * 32 + lg * 8) ^ ((lc & 7) << 3));
        const short8 ahi = *(const short8*)&Ahi[aoff];
        const short8 alo = *(const short8*)&Alo[aoff];
#pragma unroll
        for (int nt = 0; nt < 4; ++nt) {
            size_t bo = (size_t)(col0 + nt*16 + lc) * 256 + kc*32 + lg*8;
            const short8 bhi = *(const short8*)(wzd_hi + bo);
            const short8 blo = *(const short8*)(wzd_lo + bo);
            acc[nt] = __builtin_amdgcn_mfma_f32_16x16x32_bf16(ahi, bhi, acc[nt], 0, 0, 0);
            acc[nt] = __builtin_amdgcn_mfma_f32_16x16x32_bf16(ahi, blo, acc[nt], 0, 0, 0);
            acc[nt] = __builtin_amdgcn_mfma_f32_16x16x32_bf16(alo, bhi, acc[nt], 0, 0, 0);
        }
    }
    __builtin_amdgcn_s_setprio(0);
#pragma unroll
    for (int nt = 0; nt < 4; ++nt) {
        int ncol = col0 + nt * 16 + lc;
        if (ncol < HD) {
            float bias = bm1[ncol];
            float vals[4] = {acc[nt].x, acc[nt].y, acc[nt].z, acc[nt].w};
#pragma unroll
            for (int r = 0; r < 4; ++r)
                Zd[(size_t)(n0 + mw*16 + lg*4 + r) * HD + ncol] = vals[r] + bias;
        }
    }

    if (n0 < NA) {
#pragma unroll
        for (int nt = 0; nt < 4; ++nt) acc[nt] = (f32x4){0.f, 0.f, 0.f, 0.f};
        __builtin_amdgcn_s_setprio(1);
#pragma unroll
        for (int kc = 0; kc < 8; ++kc) {
            int aoff = arow + ((kc * 32 + lg * 8) ^ ((lc & 7) << 3));
            const short8 ahi = *(const short8*)&Ahi[aoff];
            const short8 alo = *(const short8*)&Alo[aoff];
#pragma unroll
            for (int nt = 0; nt < 4; ++nt) {
                size_t bo = (size_t)(col0 + nt*16 + lc) * 256 + kc*32 + lg*8;
                const short8 bhi = *(const short8*)(wzs_hi + bo);
                const short8 blo = *(const short8*)(wzs_lo + bo);
                acc[nt] = __builtin_amdgcn_mfma_f32_16x16x32_bf16(ahi, bhi, acc[nt], 0, 0, 0);
                acc[nt] = __builtin_amdgcn_mfma_f32_16x16x32_bf16(ahi, blo, acc[nt], 0, 0, 0);
                acc[nt] = __builtin_amdgcn_mfma_f32_16x16x32_bf16(alo, bhi, acc[nt], 0, 0, 0);
            }
        }
        __builtin_amdgcn_s_setprio(0);
#pragma unroll
        for (int nt = 0; nt < 4; ++nt) {
            int ncol = col0 + nt * 16 + lc;
            if (ncol < HD) {
                float vals[4] = {acc[nt].x, acc[nt].y, acc[nt].z, acc[nt].w};
#pragma unroll
                for (int r = 0; r < 4; ++r)
                    Zs[(size_t)(n0 + mw*16 + lg*4 + r) * HD + ncol] = vals[r];
            }
        }
    }
}

// ---------------- fused grid-edge message MLP: 512 threads, 3 rows/thread assembly, 8-wave GEMM ----------------
__global__ __launch_bounds__(512) void msg_gemm_kernel(
        const float* __restrict__ Zs, const float* __restrict__ Zd,
        const int* __restrict__ nbg,
        const float4* __restrict__ eaA, const float4* __restrict__ eaB,
        const float* __restrict__ eaC,
        const float* __restrict__ emask, const float* __restrict__ Wea,
        const short* __restrict__ wm2t, const float* __restrict__ bm2,
        float* __restrict__ agg) {
    __shared__ __align__(16) short Abuf[48 * 256];   // 24KB, XOR-swizzled
    __shared__ __align__(16) float mkbuf[48];
    int tid = threadIdx.x;                            // 0..511
    int blk = blockIdx.x;
    int e0 = blk * 48;

    int q = tid & 31;        // col group (q<30 active; 30,31 write zero-pad)
    int rh = tid >> 5;       // 0..15 row-threads, 3 rows each
    float4 w0[9], w1[9];
    float4 zdA0, zdA1, zdB0, zdB1;
    int srcs[3];
    if (q < 30) {
        int j = q * 8;
#pragma unroll
        for (int a = 0; a < 9; ++a) {
            w0[a] = *(const float4*)(Wea + a * HD + j);
            w1[a] = *(const float4*)(Wea + a * HD + j + 4);
        }
#pragma unroll
        for (int r8 = 0; r8 < 3; ++r8) srcs[r8] = nbg[e0 + rh + r8 * 16];
        int dn0 = NA + blk * 2;
        zdA0 = *(const float4*)(Zd + (size_t)dn0 * HD + j);
        zdA1 = *(const float4*)(Zd + (size_t)dn0 * HD + j + 4);
        zdB0 = *(const float4*)(Zd + (size_t)(dn0 + 1) * HD + j);
        zdB1 = *(const float4*)(Zd + (size_t)(dn0 + 1) * HD + j + 4);
    }
    if (tid < 48) mkbuf[tid] = emask[EAE + e0 + tid];

#pragma unroll
    for (int r8 = 0; r8 < 3; ++r8) {
        int row = rh + r8 * 16;
        i32x4 oi = (i32x4){0, 0, 0, 0};
        if (q < 30) {
            int j = q * 8;
            int eg = e0 + row;
            int srcn = srcs[r8];
            const float4 zs0 = *(const float4*)(Zs + (size_t)srcn * HD + j);
            const float4 zs1 = *(const float4*)(Zs + (size_t)srcn * HD + j + 4);
            const float4 zd0 = (row < KGK) ? zdA0 : zdB0;
            const float4 zd1 = (row < KGK) ? zdA1 : zdB1;
            float s0 = zs0.x + zd0.x, s1 = zs0.y + zd0.y, s2 = zs0.z + zd0.z, s3 = zs0.w + zd0.w;
            float s4 = zs1.x + zd1.x, s5 = zs1.y + zd1.y, s6 = zs1.z + zd1.z, s7 = zs1.w + zd1.w;
            const float4 ea0 = eaA[EAE + eg];
            const float4 ea1 = eaB[EAE + eg];
            const float  ea8 = eaC[EAE + eg];
            float ev[9] = {ea0.x, ea0.y, ea0.z, ea0.w, ea1.x, ea1.y, ea1.z, ea1.w, ea8};
#pragma unroll
            for (int a = 0; a < 9; ++a) {
                float e = ev[a];
                s0 += e * w0[a].x; s1 += e * w0[a].y; s2 += e * w0[a].z; s3 += e * w0[a].w;
                s4 += e * w1[a].x; s5 += e * w1[a].y; s6 += e * w1[a].z; s7 += e * w1[a].w;
            }
            oi[0] = (int)cvt_pk_bf16(silu_f(s0), silu_f(s1));
            oi[1] = (int)cvt_pk_bf16(silu_f(s2), silu_f(s3));
            oi[2] = (int)cvt_pk_bf16(silu_f(s4), silu_f(s5));
            oi[3] = (int)cvt_pk_bf16(silu_f(s6), silu_f(s7));
        }
        *(i32x4*)((char*)Abuf + row * 512 + ((q * 16) ^ ((row & 7) << 4))) = oi;
    }
    __syncthreads();

    int wid = tid >> 6, lane = tid & 63;   // 8 waves
    int lg = lane >> 4, lc = lane & 15;
    int col0 = wid * 32;                   // 8 N-eighths of 32 cols

    f32x4 acc[3][2];
#pragma unroll
    for (int mt = 0; mt < 3; ++mt)
#pragma unroll
        for (int nt = 0; nt < 2; ++nt) acc[mt][nt] = (f32x4){0.f, 0.f, 0.f, 0.f};

    __builtin_amdgcn_s_setprio(1);
#pragma unroll
    for (int kc = 0; kc < 8; ++kc) {
        short8 af[3];
#pragma unroll
        for (int mt = 0; mt < 3; ++mt)
            af[mt] = *(const short8*)&Abuf[(mt*16 + lc) * 256 +
                                           ((kc*32 + lg*8) ^ ((lc & 7) << 3))];
#pragma unroll
        for (int nt = 0; nt < 2; ++nt) {
            const short8 bf = *(const short8*)(wm2t + (size_t)(col0 + nt*16 + lc) * 256 + kc*32 + lg*8);
#pragma unroll
            for (int mt = 0; mt < 3; ++mt)
                acc[mt][nt] = __builtin_amdgcn_mfma_f32_16x16x32_bf16(af[mt], bf, acc[mt][nt], 0, 0, 0);
        }
    }
    __builtin_amdgcn_s_setprio(0);

#pragma unroll
    for (int nt = 0; nt < 2; ++nt) {
        int ncol = col0 + nt * 16 + lc;
        float bias = (ncol < HD) ? bm2[ncol] : 0.f;
        float p[3];
#pragma unroll
        for (int mt = 0; mt < 3; ++mt) {
            const float4 mkv = *(const float4*)&mkbuf[mt*16 + lg*4];
            float t0 = silu_f(acc[mt][nt].x + bias) * mkv.x;
            float t1 = silu_f(acc[mt][nt].y + bias) * mkv.y;
            float t2 = silu_f(acc[mt][nt].z + bias) * mkv.z;
            float t3 = silu_f(acc[mt][nt].w + bias) * mkv.w;
            p[mt] = (t0 + t1) + (t2 + t3);
        }
        float v0 = p[0] + ((lg < 2) ? p[1] : 0.f);
        float v1 = ((lg >= 2) ? p[1] : 0.f) + p[2];
        v0 += __shfl_xor(v0, 16); v0 += __shfl_xor(v0, 32);
        v1 += __shfl_xor(v1, 16); v1 += __shfl_xor(v1, 32);
        if (ncol < HD) {
            int node = NA + blk * 2;
            if (lane < 16)      agg[(size_t)(node + 0) * HD + ncol] = v0;
            else if (lane < 32) agg[(size_t)(node + 1) * HD + ncol] = v1;
        }
    }
}

// ---------------- fused message MLP for ATOM edges ----------------
template <int KE, int NPB>
__global__ __launch_bounds__(192) void msg_mfma_kernel(
        const float* __restrict__ Zs, const float* __restrict__ Zd,
        const int* __restrict__ nbrList,
        const float4* __restrict__ eaA, const float4* __restrict__ eaB,
        const float* __restrict__ eaC,
        const float* __restrict__ emask, const float* __restrict__ Wea,
        const short* __restrict__ wm2t, const float* __restrict__ bm2,
        float* __restrict__ agg, int dstBase, int edgeBase) {
    constexpr int ROWS = KE * NPB;
    constexpr int MT = ROWS / 16;
    __shared__ __align__(16) short Abuf[ROWS * 264];
    __shared__ __align__(16) float mkbuf[ROWS];

    int tid = threadIdx.x;
    int b = blockIdx.x;
    int e0 = edgeBase + b * ROWS;

    if (tid < ROWS) mkbuf[tid] = emask[e0 + tid];
    for (int idx = tid; idx < ROWS * 24; idx += 192) {
        int r = idx / 24;
        Abuf[r * 264 + 240 + (idx % 24)] = 0;
    }
    for (int idx = tid; idx < ROWS * 60; idx += 192) {
        int row = idx / 60;
        int j = (idx % 60) * 4;
        int srcn = nbrList[b * ROWS + row];
        int dstn = dstBase + b * NPB + row / KE;
        const float4 zs = *(const float4*)(Zs + (size_t)srcn * HD + j);
        const float4 zd = *(const float4*)(Zd + (size_t)dstn * HD + j);
        float s0 = zs.x + zd.x, s1 = zs.y + zd.y, s2 = zs.z + zd.z, s3 = zs.w + zd.w;
        const float4 ea0 = eaA[e0 + row];
        const float4 ea1 = eaB[e0 + row];
        const float  ea8 = eaC[e0 + row];
        float ev[9] = {ea0.x, ea0.y, ea0.z, ea0.w, ea1.x, ea1.y, ea1.z, ea1.w, ea8};
#pragma unroll
        for (int a = 0; a < 9; ++a) {
            float e = ev[a];
            const float4 w = *(const float4*)(Wea + a * HD + j);
            s0 += e * w.x; s1 += e * w.y; s2 += e * w.z; s3 += e * w.w;
        }
        short4v o;
        o.x = f2bf(silu_f(s0)); o.y = f2bf(silu_f(s1));
        o.z = f2bf(silu_f(s2)); o.w = f2bf(silu_f(s3));
        *(short4v*)&Abuf[row * 264 + j] = o;
    }
    __syncthreads();

    int w = tid / 64, lane = tid % 64;
    int lg = lane >> 4, lc = lane & 15;
    int wcol0 = w * 80;

    f32x4 acc[MT][5];
#pragma unroll
    for (int mt = 0; mt < MT; ++mt)
#pragma unroll
        for (int nt = 0; nt < 5; ++nt) acc[mt][nt] = (f32x4){0.f, 0.f, 0.f, 0.f};

#pragma unroll
    for (int kc = 0; kc < 8; ++kc) {
        short8 af[MT];
#pragma unroll
        for (int mt = 0; mt < MT; ++mt)
            af[mt] = *(const short8*)&Abuf[(mt * 16 + lc) * 264 + kc * 32 + lg * 8];
#pragma unroll
        for (int nt = 0; nt < 5; ++nt) {
            const short8 bf = *(const short8*)(wm2t + (size_t)(wcol0 + nt * 16 + lc) * 256 + kc * 32 + lg * 8);
#pragma unroll
            for (int mt = 0; mt < MT; ++mt)
                acc[mt][nt] = __builtin_amdgcn_mfma_f32_16x16x32_bf16(af[mt], bf, acc[mt][nt], 0, 0, 0);
        }
    }

#pragma unroll
    for (int nt = 0; nt < 5; ++nt) {
        int ncol = wcol0 + nt * 16 + lc;
        float bias = bm2[ncol];
        float p[MT];
#pragma unroll
        for (int mt = 0; mt < MT; ++mt) {
            const float4 mkv = *(const float4*)&mkbuf[mt * 16 + lg * 4];
            float t0 = silu_f(acc[mt][nt].x + bias) * mkv.x;
            float t1 = silu_f(acc[mt][nt].y + bias) * mkv.y;
            float t2 = silu_f(acc[mt][nt].z + bias) * mkv.z;
            float t3 = silu_f(acc[mt][nt].w + bias) * mkv.w;
            p[mt] = (t0 + t1) + (t2 + t3);
        }
#pragma unroll
        for (int mt = 0; mt < MT; ++mt) {
            float v = p[mt];
            v += __shfl_xor(v, 16);
            if (lane < 16)
                agg[(size_t)(dstBase + b * (2 * MT) + 2 * mt + 0) * HD + ncol] = v;
            else if (lane >= 32 && lane < 48)
                agg[(size_t)(dstBase + b * (2 * MT) + 2 * mt + 1) * HD + ncol] = v;
        }
    }
}

// ---------------- MFMA node update, 512 threads / 8 waves ----------------
__global__ __launch_bounds__(512) void update_mfma_kernel(
        float* __restrict__ h, const float* __restrict__ agg,
        const float* __restrict__ attr,
        const short* __restrict__ wu1t, const float* __restrict__ bu1,
        const short* __restrict__ wu2t, const float* __restrict__ bu2) {
    __shared__ __align__(16) short Abuf[32 * 512];
    __shared__ __align__(16) short Ubuf[32 * 256];
    int tid = threadIdx.x;
    int n0 = blockIdx.x * 32;

#pragma unroll
    for (int it = 0; it < 4; ++it) {
        int idx = it * 512 + tid;
        int row = idx >> 6, q = idx & 63;
        int j = q * 8;
        int n = n0 + row;
        short8 o = {0,0,0,0,0,0,0,0};
        if (j < 240) {
            const float4 a0 = *(const float4*)(h + (size_t)n * HD + j);
            const float4 a1 = *(const float4*)(h + (size_t)n * HD + j + 4);
            o[0]=f2bf(a0.x); o[1]=f2bf(a0.y); o[2]=f2bf(a0.z); o[3]=f2bf(a0.w);
            o[4]=f2bf(a1.x); o[5]=f2bf(a1.y); o[6]=f2bf(a1.z); o[7]=f2bf(a1.w);
        } else if (j < 480) {
            const float4 a0 = *(const float4*)(agg + (size_t)n * HD + (j - 240));
            const float4 a1 = *(const float4*)(agg + (size_t)n * HD + (j - 240) + 4);
            o[0]=f2bf(a0.x); o[1]=f2bf(a0.y); o[2]=f2bf(a0.z); o[3]=f2bf(a0.w);
            o[4]=f2bf(a1.x); o[5]=f2bf(a1.y); o[6]=f2bf(a1.z); o[7]=f2bf(a1.w);
        } else if (j == 480) {
#pragma unroll
            for (int a = 0; a < 8; ++a) o[a] = f2bf(attr[n*9 + a]);
        } else if (j == 488) {
            o[0] = f2bf(attr[n*9 + 8]);
        }
        *(short8*)((char*)Abuf + row * 1024 + ((q * 16) ^ ((row & 7) << 4))) = o;
    }
    __syncthreads();

    int wid = tid >> 6, lane = tid & 63;     // 8 waves
    int mw = wid >> 2, nw = wid & 3;          // 2 M-slices x 4 N-quarters
    int lg = lane >> 4, lc = lane & 15;
    int col0 = nw * 64;

    f32x4 acc[4];
#pragma unroll
    for (int nt = 0; nt < 4; ++nt) acc[nt] = (f32x4){0.f, 0.f, 0.f, 0.f};
    __builtin_amdgcn_s_setprio(1);
#pragma unroll
    for (int kc = 0; kc < 16; ++kc) {
        const short8 af = *(const short8*)((char*)Abuf + (mw*16 + lc) * 1024 +
                                           ((kc*64 + lg*16) ^ ((lc & 7) << 4)));
#pragma unroll
        for (int nt = 0; nt < 4; ++nt) {
            const short8 bf = *(const short8*)(wu1t + (size_t)(col0 + nt*16 + lc) * 512 + kc*32 + lg*8);
            acc[nt] = __builtin_amdgcn_mfma_f32_16x16x32_bf16(af, bf, acc[nt], 0, 0, 0);
        }
    }
    __builtin_amdgcn_s_setprio(0);
#pragma unroll
    for (int nt = 0; nt < 4; ++nt) {
        int ncol = col0 + nt * 16 + lc;
        float bias = (ncol < HD) ? bu1[ncol] : 0.f;
        float vals[4] = {acc[nt].x, acc[nt].y, acc[nt].z, acc[nt].w};
#pragma unroll
        for (int r = 0; r < 4; ++r) {
            int row = mw*16 + lg*4 + r;
            *(short*)((char*)Ubuf + row * 512 + ((ncol * 2) ^ ((row & 7) << 4))) =
                f2bf(silu_f(vals[r] + bias));
        }
    }
    __syncthreads();

    f32x4 acc2[4];
#pragma unroll
    for (int nt = 0; nt < 4; ++nt) acc2[nt] = (f32x4){0.f, 0.f, 0.f, 0.f};
    __builtin_amdgcn_s_setprio(1);
#pragma unroll
    for (int kc = 0; kc < 8; ++kc) {
        const short8 af = *(const short8*)((char*)Ubuf + (mw*16 + lc) * 512 +
                                           ((kc*64 + lg*16) ^ ((lc & 7) << 4)));
#pragma unroll
        for (int nt = 0; nt < 4; ++nt) {
            const short8 bf = *(const short8*)(wu2t + (size_t)(col0 + nt*16 + lc) * 256 + kc*32 + lg*8);
            acc2[nt] = __builtin_amdgcn_mfma_f32_16x16x32_bf16(af, bf, acc2[nt], 0, 0, 0);
        }
    }
    __builtin_amdgcn_s_setprio(0);
#pragma unroll
    for (int nt = 0; nt < 4; ++nt) {
        int ncol = col0 + nt * 16 + lc;
        if (ncol < HD) {
            float bias = bu2[ncol];
            float vals[4] = {acc2[nt].x, acc2[nt].y, acc2[nt].z, acc2[nt].w};
#pragma unroll
            for (int r = 0; r < 4; ++r) {
                int row = mw*16 + lg*4 + r;
                size_t hi = (size_t)(n0 + row) * HD + ncol;
                h[hi] += silu_f(vals[r] + bias);
            }
        }
    }
}

// ---------------- readout (grid nodes only) ----------------
__global__ void output_kernel(const float* __restrict__ h,
                              const float* __restrict__ Wo1, const float* __restrict__ bo1,
                              const float* __restrict__ Wo2, const float* __restrict__ bo2,
                              float* __restrict__ out) {
    const int NBT = 4;
    __shared__ float hr[NBT][HD];
    __shared__ float o1[NBT][HD];
    int tid = threadIdx.x;
    int g0 = blockIdx.x * NBT;
    for (int idx = tid; idx < NBT * HD; idx += 256) {
        int k = idx / HD, i = idx % HD;
        hr[k][i] = h[(size_t)(NA + g0 + k) * HD + i];
    }
    __syncthreads();
    int j = tid;
    if (j < HD) {
        float acc[NBT] = {0.f, 0.f, 0.f, 0.f};
        for (int i4 = 0; i4 < 60; ++i4) {
            int i = 4 * i4;
            float w0 = Wo1[(i+0)*HD+j], w1 = Wo1[(i+1)*HD+j];
            float w2 = Wo1[(i+2)*HD+j], w3 = Wo1[(i+3)*HD+j];
#pragma unroll
            for (int k = 0; k < NBT; ++k) {
                const float4 a = *reinterpret_cast<const float4*>(&hr[k][i]);
                acc[k] += a.x*w0 + a.y*w1 + a.z*w2 + a.w*w3;
            }
        }
        float bb = bo1[j];
#pragma unroll
        for (int k = 0; k < NBT; ++k) o1[k][j] = silu_f(acc[k] + bb);
    }
    __syncthreads();
    if (tid < NBT * CD) {
        int k = tid >> 5, c = tid & 31;
        float acc = bo2[c];
        for (int i = 0; i < HD; ++i) acc += o1[k][i] * Wo2[i*CD + c];
        out[(size_t)(g0 + k) * CD + c] = acc;
    }
}

extern "C" void kernel_launch(void* const* d_in, const int* in_sizes, int n_in,
                              void* d_out, int out_size, void* d_ws, size_t ws_size,
                              hipStream_t stream) {
    (void)in_sizes; (void)n_in; (void)out_size; (void)ws_size;
    const float* pos   = (const float*)d_in[0];
    const int*   types = (const int*)d_in[1];
    const int*   batch = (const int*)d_in[2];
    (void)batch;
    const float* We    = (const float*)d_in[3];
    const float* be    = (const float*)d_in[4];
    const float* Wm1   = (const float*)d_in[5];
    const float* bm1   = (const float*)d_in[6];
    const float* Wm2   = (const float*)d_in[7];
    const float* bm2   = (const float*)d_in[8];
    const float* Wu1   = (const float*)d_in[9];
    const float* bu1   = (const float*)d_in[10];
    const float* Wu2   = (const float*)d_in[11];
    const float* bu2   = (const float*)d_in[12];
    const float* Wo1   = (const float*)d_in[13];
    const float* bo1   = (const float*)d_in[14];
    const float* Wo2   = (const float*)d_in[15];
    const float* bo2   = (const float*)d_in[16];
    float* out = (float*)d_out;

    char* ws = (char*)d_ws;
    size_t off = 0;
    auto take = [&](size_t bytes) -> char* {
        char* p = ws + off;
        off = (off + bytes + 255) & ~(size_t)255;
        return p;
    };
    int*    nbr    = (int*)take((size_t)EAE * 4);
    int*    nbg    = (int*)take((size_t)EGE * 4);
    float4* eaA    = (float4*)take((size_t)ET * 16);
    float4* eaB    = (float4*)take((size_t)ET * 16);
    float*  eaC    = (float*)take((size_t)ET * 4);
    float*  emask  = (float*)take((size_t)ET * 4);
    float*  attr   = (float*)take((size_t)NN * 9 * 4);
    float*  h      = (float*)take((size_t)NN * HD * 4);
    float*  agg    = (float*)take((size_t)NN * HD * 4);
    float*  zs     = (float*)take((size_t)NA * HD * 4);
    float*  zd     = (float*)take((size_t)NN * HD * 4);
    short*  wm2t   = (short*)take((size_t)2 * 256 * 256 * 2);
    short*  wu1t   = (short*)take((size_t)2 * 256 * 512 * 2);
    short*  wu2t   = (short*)take((size_t)2 * 256 * 256 * 2);
    short*  wzd_hi = (short*)take((size_t)2 * 256 * 256 * 2);
    short*  wzd_lo = (short*)take((size_t)2 * 256 * 256 * 2);
    short*  wzs_hi = (short*)take((size_t)2 * 256 * 256 * 2);
    short*  wzs_lo = (short*)take((size_t)2 * 256 * 256 * 2);

    knn_kernel<<<NA/4 + NG/4, 256, 0, stream>>>(pos, nbr, nbg);
    edge_kernel<<<ET/256, 256, 0, stream>>>(pos, nbr, nbg, eaA, eaB, eaC, emask);
    node_attr_kernel<<<NN/256, 256, 0, stream>>>(eaA, eaB, eaC, emask, attr);
    encoder_kernel<<<(NN*HD)/256, 256, 0, stream>>>(types, attr, We, be, h);
    convert_all_kernel<<<786432/256, 256, 0, stream>>>(Wm2, Wu1, Wu2, Wm1,
                                                       wm2t, wu1t, wu2t,
                                                       wzd_hi, wzd_lo, wzs_hi, wzs_lo);

    for (int l = 0; l < 2; ++l) {
        const float* wm1 = Wm1 + (size_t)l * DIN * HD;
        const float* wea = wm1 + (size_t)480 * HD;
        const short* w2t = wm2t + (size_t)l * 256 * 256;
        const float* bb2 = bm2 + l * HD;
        node_z_mfma_kernel<<<NN/32, 512, 0, stream>>>(
            h,
            wzd_hi + (size_t)l * 65536, wzd_lo + (size_t)l * 65536,
            wzs_hi + (size_t)l * 65536, wzs_lo + (size_t)l * 65536,
            bm1 + l * HD, zs, zd);
        msg_mfma_kernel<KAK, 8><<<NA*KAK/64, 192, 0, stream>>>(
            zs, zd, nbr, eaA, eaB, eaC, emask, wea, w2t, bb2, agg, 0, 0);
        msg_gemm_kernel<<<EGE/48, 512, 0, stream>>>(zs, zd, nbg, eaA, eaB, eaC,
                                                    emask, wea, w2t, bb2, agg);
        update_mfma_kernel<<<NN/32, 512, 0, stream>>>(
            h, agg, attr,
            wu1t + (size_t)l * 256 * 512, bu1 + l * HD,
            wu2t + (size_t)l * 256 * 256, bu2 + l * HD);
    }
    output_kernel<<<NG/4, 256, 0, stream>>>(h, Wo1, bo1, Wo2, bo2, out);
}